// Round 1
// baseline (727.005 us; speedup 1.0000x reference)
//
#include <hip/hip_runtime.h>
#include <math.h>

// Problem constants
#define NCAM 6
#define BSZ 2
#define SQL 1024      // query spatial (32x32)
#define SKL 1680      // key spatial (28x60)
#define NHEAD 4
#define DHEAD 32

// ---------------------------------------------------------------------------
// Projection: LN(x) @ W + b, split heads, optional scale.
// x: (B*N, 128, S) channel-major; out: (b, m, n, pos, 32)
// 128 threads, 8 positions per block.
// ---------------------------------------------------------------------------
__global__ __launch_bounds__(128) void proj_kernel(
    const float* __restrict__ x, const float* __restrict__ gamma,
    const float* __restrict__ beta, const float* __restrict__ W,
    const float* __restrict__ bias, float scale,
    float* __restrict__ out, int S) {
  const int d = threadIdx.x;            // channel 0..127
  const int p0 = blockIdx.x * 8;        // global position base (S % 8 == 0)
  const int bn = p0 / S;
  const int pos0 = p0 - bn * S;
  const int b = bn / NCAM, n = bn - b * NCAM;

  __shared__ __align__(16) float sX[8][128];
  __shared__ float sMu[8], sRs[8];

  const float* xb = x + ((size_t)(bn * 128 + d)) * S + pos0;
  float4 x0 = *((const float4*)xb);
  float4 x1 = *((const float4*)(xb + 4));
  sX[0][d] = x0.x; sX[1][d] = x0.y; sX[2][d] = x0.z; sX[3][d] = x0.w;
  sX[4][d] = x1.x; sX[5][d] = x1.y; sX[6][d] = x1.z; sX[7][d] = x1.w;
  __syncthreads();

  {  // stats: 16 lanes per position, one-pass mean/var
    const int pos = d >> 4, j = d & 15;
    float s1 = 0.f, s2 = 0.f;
#pragma unroll
    for (int i = 0; i < 8; ++i) { float v = sX[pos][j + 16 * i]; s1 += v; s2 += v * v; }
#pragma unroll
    for (int msk = 1; msk <= 8; msk <<= 1) {
      s1 += __shfl_xor(s1, msk, 64);
      s2 += __shfl_xor(s2, msk, 64);
    }
    if (j == 0) {
      float mu = s1 * (1.f / 128.f);
      sMu[pos] = mu;
      sRs[pos] = rsqrtf(s2 * (1.f / 128.f) - mu * mu + 1e-5f);
    }
  }
  __syncthreads();
  {
    float gg = gamma[d], bb = beta[d];
#pragma unroll
    for (int i = 0; i < 8; ++i) sX[i][d] = (sX[i][d] - sMu[i]) * sRs[i] * gg + bb;
  }
  __syncthreads();

  // GEMV: output channel c = d, 8 positions in registers
  float acc[8];
  float bc = bias[d];
#pragma unroll
  for (int i = 0; i < 8; ++i) acc[i] = bc;
  const float* Wc = W + d;
#pragma unroll 4
  for (int dd = 0; dd < 128; ++dd) {
    float w = Wc[dd * 128];
#pragma unroll
    for (int i = 0; i < 8; ++i) acc[i] = fmaf(sX[i][dd], w, acc[i]);
  }
  const int m = d >> 5, ch = d & 31;
  size_t ob = ((((size_t)(b * NHEAD + m) * NCAM + n) * S) + pos0) * 32 + ch;
#pragma unroll
  for (int i = 0; i < 8; ++i) out[ob + (size_t)i * 32] = acc[i] * scale;
}

// ---------------------------------------------------------------------------
// Flash attention across cameras. Grid: 8 bm * 32 q-tiles. 256 threads.
// Qh/Kh/Vh layout: (bm, n, pos, 32). A out: (b, qpos, m, 32).
// ---------------------------------------------------------------------------
__global__ __launch_bounds__(256) void attn_kernel(
    const float* __restrict__ Qh, const float* __restrict__ Kh,
    const float* __restrict__ Vh, float* __restrict__ A) {
  const int t = threadIdx.x;
  const int bm = blockIdx.x >> 5;
  const int q0 = (blockIdx.x & 31) * 32;

  __shared__ __align__(16) float sK[64][36];   // pad 36: 4-way worst on reads
  __shared__ __align__(16) float sV[64][36];
  __shared__ float sP[32][65];                 // pad 65: conflict-free across q
  __shared__ float sM[32], sL[32], sAl[32];

  if (t < 32) { sM[t] = -1e30f; sL[t] = 0.f; sAl[t] = 0.f; }

  float a0 = 0.f, a1 = 0.f, a2 = 0.f, a3 = 0.f;

  const int qg = t >> 4, kg = t & 15;          // QK mapping: 2q x 4k
  const int qa = 2 * qg, qb = qa + 1;
  const int pq = t >> 3, pc = (t & 7) * 4;     // PV mapping: 1q x 4ch

  for (int n = 0; n < NCAM; ++n) {
    // camera-specific query vectors in registers
    float4 qA[8], qB[8];
    const float4* Qb = (const float4*)(Qh + ((size_t)(bm * NCAM + n) * SQL + q0) * 32);
#pragma unroll
    for (int cc = 0; cc < 8; ++cc) { qA[cc] = Qb[qa * 8 + cc]; qB[cc] = Qb[qb * 8 + cc]; }
    const float* Kb = Kh + (size_t)(bm * NCAM + n) * SKL * 32;
    const float* Vb = Vh + (size_t)(bm * NCAM + n) * SKL * 32;

    for (int kt = 0; kt < 27; ++kt) {          // 26*64 + 16 = 1680
      const int kbase = kt * 64;
      int valid = SKL - kbase; if (valid > 64) valid = 64;
      __syncthreads();                         // protect prev tile's sP/sV reads
      // stage K/V tile: 512 float4 each, 2 per thread
#pragma unroll
      for (int r = 0; r < 2; ++r) {
        int f = t + r * 256;
        int key = f >> 3, cc = f & 7;
        float4 kv = make_float4(0.f, 0.f, 0.f, 0.f), vv = kv;
        if (key < valid) {
          kv = ((const float4*)(Kb + (size_t)(kbase + key) * 32))[cc];
          vv = ((const float4*)(Vb + (size_t)(kbase + key) * 32))[cc];
        }
        *((float4*)&sK[key][cc * 4]) = kv;
        *((float4*)&sV[key][cc * 4]) = vv;
      }
      __syncthreads();

      // QK: 2 queries x 4 keys per thread
      float dA[4] = {0.f, 0.f, 0.f, 0.f}, dB[4] = {0.f, 0.f, 0.f, 0.f};
#pragma unroll
      for (int kk = 0; kk < 4; ++kk) {
        const int krow = kg * 4 + kk;
#pragma unroll
        for (int cc = 0; cc < 8; ++cc) {
          float4 k4 = *((const float4*)&sK[krow][cc * 4]);
          dA[kk] = fmaf(qA[cc].x, k4.x, dA[kk]);
          dA[kk] = fmaf(qA[cc].y, k4.y, dA[kk]);
          dA[kk] = fmaf(qA[cc].z, k4.z, dA[kk]);
          dA[kk] = fmaf(qA[cc].w, k4.w, dA[kk]);
          dB[kk] = fmaf(qB[cc].x, k4.x, dB[kk]);
          dB[kk] = fmaf(qB[cc].y, k4.y, dB[kk]);
          dB[kk] = fmaf(qB[cc].z, k4.z, dB[kk]);
          dB[kk] = fmaf(qB[cc].w, k4.w, dB[kk]);
        }
        if (krow >= valid) { dA[kk] = -1e30f; dB[kk] = -1e30f; }
      }

      // online softmax (16-lane groups own one q-pair)
      float mA = fmaxf(fmaxf(dA[0], dA[1]), fmaxf(dA[2], dA[3]));
      float mB = fmaxf(fmaxf(dB[0], dB[1]), fmaxf(dB[2], dB[3]));
#pragma unroll
      for (int msk = 1; msk <= 8; msk <<= 1) {
        mA = fmaxf(mA, __shfl_xor(mA, msk, 64));
        mB = fmaxf(mB, __shfl_xor(mB, msk, 64));
      }
      const float moA = sM[qa], moB = sM[qb];
      const float mnA = fmaxf(moA, mA), mnB = fmaxf(moB, mB);
      const float alA = __expf(moA - mnA), alB = __expf(moB - mnB);
      float pA[4], pB[4], ltA = 0.f, ltB = 0.f;
#pragma unroll
      for (int kk = 0; kk < 4; ++kk) {
        pA[kk] = __expf(dA[kk] - mnA); ltA += pA[kk];
        pB[kk] = __expf(dB[kk] - mnB); ltB += pB[kk];
      }
#pragma unroll
      for (int msk = 1; msk <= 8; msk <<= 1) {
        ltA += __shfl_xor(ltA, msk, 64);
        ltB += __shfl_xor(ltB, msk, 64);
      }
#pragma unroll
      for (int kk = 0; kk < 4; ++kk) {
        sP[qa][kg * 4 + kk] = pA[kk];
        sP[qb][kg * 4 + kk] = pB[kk];
      }
      if (kg == 0) {
        sM[qa] = mnA; sL[qa] = sL[qa] * alA + ltA; sAl[qa] = alA;
        sM[qb] = mnB; sL[qb] = sL[qb] * alB + ltB; sAl[qb] = alB;
      }
      __syncthreads();

      // PV: 1 query x 4 channels per thread
      const float al = sAl[pq];
      a0 *= al; a1 *= al; a2 *= al; a3 *= al;
#pragma unroll 8
      for (int kk = 0; kk < 64; ++kk) {
        const float p = sP[pq][kk];
        const float4 v4 = *((const float4*)&sV[kk][pc]);
        a0 = fmaf(p, v4.x, a0);
        a1 = fmaf(p, v4.y, a1);
        a2 = fmaf(p, v4.z, a2);
        a3 = fmaf(p, v4.w, a3);
      }
    }
  }

  const float inv = 1.f / sL[pq];
  const int b = bm >> 2, m = bm & 3;
  float4 o = make_float4(a0 * inv, a1 * inv, a2 * inv, a3 * inv);
  *((float4*)&A[(((size_t)b * SQL + q0 + pq) * NHEAD + m) * 32 + pc]) = o;
}

// ---------------------------------------------------------------------------
// Head merge -> Wp -> +skip -> preLN -> MLP(gelu exact) -> postLN -> out
// One block (256 thr) per (b, qpos).
// ---------------------------------------------------------------------------
__global__ __launch_bounds__(256) void post_kernel(
    const float* __restrict__ Abuf, const float* __restrict__ skip,
    const float* __restrict__ Wp, const float* __restrict__ bp,
    const float* __restrict__ pre_g, const float* __restrict__ pre_b,
    const float* __restrict__ W1, const float* __restrict__ b1,
    const float* __restrict__ W2, const float* __restrict__ b2,
    const float* __restrict__ post_g, const float* __restrict__ post_b,
    float* __restrict__ out) {
  const int t = threadIdx.x;
  const int b = blockIdx.x >> 10;
  const int qp = blockIdx.x & 1023;

  __shared__ float sa[128], sz[128], sh[256], red[256];

  if (t < 128) sa[t] = Abuf[((size_t)b * SQL + qp) * 128 + t];
  __syncthreads();

  float z = 0.f;
  if (t < 128) {
    float acc = bp[t];
#pragma unroll 4
    for (int c = 0; c < 128; ++c) acc = fmaf(sa[c], Wp[c * 128 + t], acc);
    acc += skip[((size_t)b * 128 + t) * SQL + qp];
    z = acc;
  }
  // pre-LN
  red[t] = (t < 128) ? z : 0.f;
  __syncthreads();
  for (int s = 128; s > 0; s >>= 1) { if (t < s) red[t] += red[t + s]; __syncthreads(); }
  float mu = red[0] * (1.f / 128.f);
  __syncthreads();
  float dv = (t < 128) ? (z - mu) : 0.f;
  red[t] = dv * dv;
  __syncthreads();
  for (int s = 128; s > 0; s >>= 1) { if (t < s) red[t] += red[t + s]; __syncthreads(); }
  float rstd = rsqrtf(red[0] * (1.f / 128.f) + 1e-5f);
  __syncthreads();
  if (t < 128) sz[t] = (z - mu) * rstd * pre_g[t] + pre_b[t];
  __syncthreads();

  // hidden layer (256 wide), exact GELU
  {
    float acc = b1[t];
#pragma unroll 4
    for (int c = 0; c < 128; ++c) acc = fmaf(sz[c], W1[c * 256 + t], acc);
    sh[t] = 0.5f * acc * (1.f + erff(acc * 0.70710678118654752f));
  }
  __syncthreads();

  float z2 = 0.f;
  if (t < 128) {
    float acc = b2[t];
#pragma unroll 4
    for (int c = 0; c < 256; ++c) acc = fmaf(sh[c], W2[c * 128 + t], acc);
    z2 = sz[t] + acc;
  }
  // post-LN
  red[t] = (t < 128) ? z2 : 0.f;
  __syncthreads();
  for (int s = 128; s > 0; s >>= 1) { if (t < s) red[t] += red[t + s]; __syncthreads(); }
  float mu2 = red[0] * (1.f / 128.f);
  __syncthreads();
  float dv2 = (t < 128) ? (z2 - mu2) : 0.f;
  red[t] = dv2 * dv2;
  __syncthreads();
  for (int s = 128; s > 0; s >>= 1) { if (t < s) red[t] += red[t + s]; __syncthreads(); }
  float rstd2 = rsqrtf(red[0] * (1.f / 128.f) + 1e-5f);
  if (t < 128)
    out[((size_t)b * 128 + t) * SQL + qp] = (z2 - mu2) * rstd2 * post_g[t] + post_b[t];
}

// ---------------------------------------------------------------------------
extern "C" void kernel_launch(void* const* d_in, const int* in_sizes, int n_in,
                              void* d_out, int out_size, void* d_ws, size_t ws_size,
                              hipStream_t stream) {
  const float* q_in   = (const float*)d_in[0];
  const float* k_in   = (const float*)d_in[1];
  const float* v_in   = (const float*)d_in[2];
  const float* skip   = (const float*)d_in[3];
  const float* q_ln_g = (const float*)d_in[4];
  const float* q_ln_b = (const float*)d_in[5];
  const float* Wq     = (const float*)d_in[6];
  const float* bq     = (const float*)d_in[7];
  const float* k_ln_g = (const float*)d_in[8];
  const float* k_ln_b = (const float*)d_in[9];
  const float* Wk     = (const float*)d_in[10];
  const float* bk     = (const float*)d_in[11];
  const float* v_ln_g = (const float*)d_in[12];
  const float* v_ln_b = (const float*)d_in[13];
  const float* Wv     = (const float*)d_in[14];
  const float* bv     = (const float*)d_in[15];
  const float* Wp     = (const float*)d_in[16];
  const float* bp     = (const float*)d_in[17];
  const float* pre_g  = (const float*)d_in[18];
  const float* pre_b  = (const float*)d_in[19];
  const float* W1     = (const float*)d_in[20];
  const float* b1     = (const float*)d_in[21];
  const float* W2     = (const float*)d_in[22];
  const float* b2     = (const float*)d_in[23];
  const float* post_g = (const float*)d_in[24];
  const float* post_b = (const float*)d_in[25];

  float* ws = (float*)d_ws;
  float* Qh = ws;                                             // 2*4*6*1024*32 = 1,572,864 f
  float* Kh = Qh + (size_t)BSZ * NHEAD * NCAM * SQL * 32;     // 2*4*6*1680*32 = 2,580,480 f
  float* Vh = Kh + (size_t)BSZ * NHEAD * NCAM * SKL * 32;
  float* Ab = Vh + (size_t)BSZ * NHEAD * NCAM * SKL * 32;     // 2*1024*128 f
  float* out = (float*)d_out;

  const float scale = 0.17677669529663689f;  // 1/sqrt(32), folded into Q

  proj_kernel<<<(BSZ * NCAM * SQL) / 8, 128, 0, stream>>>(q_in, q_ln_g, q_ln_b, Wq, bq, scale, Qh, SQL);
  proj_kernel<<<(BSZ * NCAM * SKL) / 8, 128, 0, stream>>>(k_in, k_ln_g, k_ln_b, Wk, bk, 1.f, Kh, SKL);
  proj_kernel<<<(BSZ * NCAM * SKL) / 8, 128, 0, stream>>>(v_in, v_ln_g, v_ln_b, Wv, bv, 1.f, Vh, SKL);
  attn_kernel<<<BSZ * NHEAD * (SQL / 32), 256, 0, stream>>>(Qh, Kh, Vh, Ab);
  post_kernel<<<BSZ * SQL, 256, 0, stream>>>(Ab, skip, Wp, bp, pre_g, pre_b,
                                             W1, b1, W2, b2, post_g, post_b, out);
}

// Round 2
// 298.963 us; speedup vs baseline: 2.4318x; 2.4318x over previous
//
#include <hip/hip_runtime.h>
#include <math.h>

// Problem constants
#define NCAM 6
#define BSZ 2
#define SQL 1024      // query spatial (32x32)
#define SKL 1680      // key spatial (28x60)
#define NHEAD 4
#define DHEAD 32

typedef __attribute__((ext_vector_type(8))) short short8;   // 8 bf16 (4 VGPRs)
typedef __attribute__((ext_vector_type(4))) float f32x4;    // MFMA C/D frag

__device__ __forceinline__ unsigned short f2bf(float x) {
  unsigned int u = __builtin_bit_cast(unsigned int, x);
  u += 0x7FFFu + ((u >> 16) & 1u);   // RNE
  return (unsigned short)(u >> 16);
}

// ---------------------------------------------------------------------------
// Projection: LN(x) @ W + b -> bf16, split heads, optional scale, optional
// transpose (for V). x: (B*N, 128, S) channel-major.
// Q/K out: (bm, n, pos, 32) bf16.   V out (vtrans=1): (bm, n, 32, S) bf16.
// 128 threads, 8 positions per block.
// ---------------------------------------------------------------------------
__global__ __launch_bounds__(128) void proj_kernel(
    const float* __restrict__ x, const float* __restrict__ gamma,
    const float* __restrict__ beta, const float* __restrict__ W,
    const float* __restrict__ bias, float scale,
    unsigned short* __restrict__ out, int S, int vtrans) {
  const int d = threadIdx.x;            // channel 0..127
  const int p0 = blockIdx.x * 8;        // global position base (S % 8 == 0)
  const int bn = p0 / S;
  const int pos0 = p0 - bn * S;
  const int b = bn / NCAM, n = bn - b * NCAM;

  __shared__ __align__(16) float sX[8][128];
  __shared__ float sMu[8], sRs[8];

  const float* xb = x + ((size_t)(bn * 128 + d)) * S + pos0;
  float4 x0 = *((const float4*)xb);
  float4 x1 = *((const float4*)(xb + 4));
  sX[0][d] = x0.x; sX[1][d] = x0.y; sX[2][d] = x0.z; sX[3][d] = x0.w;
  sX[4][d] = x1.x; sX[5][d] = x1.y; sX[6][d] = x1.z; sX[7][d] = x1.w;
  __syncthreads();

  {  // stats: 16 lanes per position, one-pass mean/var
    const int pos = d >> 4, j = d & 15;
    float s1 = 0.f, s2 = 0.f;
#pragma unroll
    for (int i = 0; i < 8; ++i) { float v = sX[pos][j + 16 * i]; s1 += v; s2 += v * v; }
#pragma unroll
    for (int msk = 1; msk <= 8; msk <<= 1) {
      s1 += __shfl_xor(s1, msk, 64);
      s2 += __shfl_xor(s2, msk, 64);
    }
    if (j == 0) {
      float mu = s1 * (1.f / 128.f);
      sMu[pos] = mu;
      sRs[pos] = rsqrtf(s2 * (1.f / 128.f) - mu * mu + 1e-5f);
    }
  }
  __syncthreads();
  {
    float gg = gamma[d], bb = beta[d];
#pragma unroll
    for (int i = 0; i < 8; ++i) sX[i][d] = (sX[i][d] - sMu[i]) * sRs[i] * gg + bb;
  }
  __syncthreads();

  // GEMV: output channel c = d, 8 positions in registers
  float acc[8];
  float bc = bias[d];
#pragma unroll
  for (int i = 0; i < 8; ++i) acc[i] = bc;
  const float* Wc = W + d;
#pragma unroll 4
  for (int dd = 0; dd < 128; ++dd) {
    float w = Wc[dd * 128];
#pragma unroll
    for (int i = 0; i < 8; ++i) acc[i] = fmaf(sX[i][dd], w, acc[i]);
  }
  const int m = d >> 5, ch = d & 31;
  const int bm = b * NHEAD + m;
  if (vtrans) {
    // (bm, n, 32ch, S): 8 consecutive positions -> one 16B store
    size_t ob = (((size_t)(bm * NCAM + n) * 32) + ch) * S + pos0;
    short8 pk;
#pragma unroll
    for (int i = 0; i < 8; ++i) pk[i] = (short)f2bf(acc[i] * scale);
    *((short8*)(out + ob)) = pk;
  } else {
    size_t ob = (((size_t)(bm * NCAM + n) * S) + pos0) * 32 + ch;
#pragma unroll
    for (int i = 0; i < 8; ++i) out[ob + (size_t)i * 32] = f2bf(acc[i] * scale);
  }
}

// ---------------------------------------------------------------------------
// MFMA flash attention (transposed formulation).
// Grid: 8 bm * 64 q-tiles = 512 blocks, 256 threads = 4 waves.
// Wave w handles the same 16 queries over key partition [w*448, w*448+448)
// of each camera (last partition: 336). No __syncthreads in the main loop.
// S^T = K·Q^T  (C: col=lane&15 -> q, row=quad*4+reg -> key)
// O^T = V^T·P^T (C: col -> q, row -> ch)
// ---------------------------------------------------------------------------
__global__ __launch_bounds__(256) void attn_mfma(
    const unsigned short* __restrict__ Qh, const unsigned short* __restrict__ Kh,
    const unsigned short* __restrict__ Vt, float* __restrict__ A) {
  const int t = threadIdx.x;
  const int w = t >> 6;          // wave = key partition
  const int l = t & 63;
  const int lq = l & 15;         // q index (and frag row/col index)
  const int quad = l >> 4;

  const int bm = blockIdx.x >> 6;
  const int qt = blockIdx.x & 63;
  const int q0 = qt * 16;

  __shared__ unsigned short sP[4][16][72];  // [wave][q][key] bf16, pitch 72 (16B-align reads)
  __shared__ float sO[4][16][36];           // [wave][q][ch] (pitch 36: pad)
  __shared__ float sMw[4][16], sLw[4][16];

  f32x4 o0 = {0.f, 0.f, 0.f, 0.f};          // ch 0..15 rows
  f32x4 o1 = {0.f, 0.f, 0.f, 0.f};          // ch 16..31 rows
  float m_cur = -1e30f, l_cur = 0.f;

  const int kstart = w * 448;
  const int kend = (kstart + 448 < SKL) ? (kstart + 448) : SKL;
  const int ntiles = (kend - kstart + 63) >> 6;

  for (int n = 0; n < NCAM; ++n) {
    const unsigned short* Qb = Qh + ((size_t)(bm * NCAM + n) * SQL + q0) * 32;
    const unsigned short* Kb = Kh + (size_t)(bm * NCAM + n) * SKL * 32;
    const unsigned short* Vb = Vt + (size_t)(bm * NCAM + n) * 32 * SKL;
    const short8 qf = *((const short8*)(Qb + lq * 32 + quad * 8));

    for (int kt = 0; kt < ntiles; ++kt) {
      const int kb = kstart + kt * 64;
      // ---- S^T: 4 mfma over 16-key sub-tiles (K-dim = dh = 32) ----
      f32x4 s[4];
#pragma unroll
      for (int st = 0; st < 4; ++st) {
        const short8 kf = *((const short8*)(Kb + (size_t)(kb + st * 16 + lq) * 32 + quad * 8));
        f32x4 z = {0.f, 0.f, 0.f, 0.f};
        s[st] = __builtin_amdgcn_mfma_f32_16x16x32_bf16(kf, qf, z, 0, 0, 0);
      }
      // ---- mask + online softmax (per-q reductions: shfl_xor 16,32) ----
      const int rem = kend - kb;
      float sv[16];
      float lm = -1e30f;
#pragma unroll
      for (int st = 0; st < 4; ++st) {
#pragma unroll
        for (int r = 0; r < 4; ++r) {
          const int key = st * 16 + quad * 4 + r;
          float v = (key < rem) ? s[st][r] : -1e30f;
          sv[st * 4 + r] = v;
          lm = fmaxf(lm, v);
        }
      }
      lm = fmaxf(lm, __shfl_xor(lm, 16, 64));
      lm = fmaxf(lm, __shfl_xor(lm, 32, 64));
      const float m_new = fmaxf(m_cur, lm);
      const float alpha = __expf(m_cur - m_new);
      float ls = 0.f;
      unsigned short pb[16];
#pragma unroll
      for (int i = 0; i < 16; ++i) {
        const float p = __expf(sv[i] - m_new);
        ls += p;
        pb[i] = f2bf(p);
      }
      ls += __shfl_xor(ls, 16, 64);
      ls += __shfl_xor(ls, 32, 64);
      m_cur = m_new;
      l_cur = l_cur * alpha + ls;
      o0 *= alpha;
      o1 *= alpha;
      // ---- P^T -> per-wave LDS (B-frag order), no barrier needed ----
#pragma unroll
      for (int st = 0; st < 4; ++st) {
        ushort4 pk = make_ushort4(pb[st * 4 + 0], pb[st * 4 + 1], pb[st * 4 + 2], pb[st * 4 + 3]);
        *((ushort4*)&sP[w][lq][st * 16 + quad * 4]) = pk;
      }
      // ---- O^T += V^T · P^T : 4 mfma (2 key-chunks x 2 ch-halves) ----
#pragma unroll
      for (int c = 0; c < 2; ++c) {
        const short8 pf = *((const short8*)&sP[w][lq][c * 32 + quad * 8]);
        const short8 v0 = *((const short8*)(Vb + (size_t)lq * SKL + kb + c * 32 + quad * 8));
        const short8 v1 = *((const short8*)(Vb + (size_t)(16 + lq) * SKL + kb + c * 32 + quad * 8));
        o0 = __builtin_amdgcn_mfma_f32_16x16x32_bf16(v0, pf, o0, 0, 0, 0);
        o1 = __builtin_amdgcn_mfma_f32_16x16x32_bf16(v1, pf, o1, 0, 0, 0);
      }
    }
  }

  // ---- flash combine across the 4 key partitions ----
  *((f32x4*)&sO[w][lq][quad * 4]) = o0;
  *((f32x4*)&sO[w][lq][16 + quad * 4]) = o1;
  if (l < 16) { sMw[w][l] = m_cur; sLw[w][l] = l_cur; }
  __syncthreads();
  if (w == 0) {
    const float m0 = sMw[0][lq], m1 = sMw[1][lq], m2 = sMw[2][lq], m3 = sMw[3][lq];
    const float mf = fmaxf(fmaxf(m0, m1), fmaxf(m2, m3));
    float lf = 0.f;
    f32x4 a0 = {0.f, 0.f, 0.f, 0.f}, a1 = {0.f, 0.f, 0.f, 0.f};
#pragma unroll
    for (int ww = 0; ww < 4; ++ww) {
      const float sc = __expf(sMw[ww][lq] - mf);
      lf += sLw[ww][lq] * sc;
      const f32x4 x0 = *((const f32x4*)&sO[ww][lq][quad * 4]);
      const f32x4 x1 = *((const f32x4*)&sO[ww][lq][16 + quad * 4]);
      a0 += x0 * sc;
      a1 += x1 * sc;
    }
    const float inv = 1.f / lf;
    const int b = bm >> 2, hm = bm & 3;
    float* outp = A + (((size_t)b * SQL + q0 + lq) * NHEAD + hm) * 32;
    *((f32x4*)(outp + quad * 4)) = a0 * inv;
    *((f32x4*)(outp + 16 + quad * 4)) = a1 * inv;
  }
}

// ---------------------------------------------------------------------------
// Head merge -> Wp -> +skip -> preLN -> MLP(gelu exact) -> postLN -> out
// One block (256 thr) per (b, qpos).
// ---------------------------------------------------------------------------
__global__ __launch_bounds__(256) void post_kernel(
    const float* __restrict__ Abuf, const float* __restrict__ skip,
    const float* __restrict__ Wp, const float* __restrict__ bp,
    const float* __restrict__ pre_g, const float* __restrict__ pre_b,
    const float* __restrict__ W1, const float* __restrict__ b1,
    const float* __restrict__ W2, const float* __restrict__ b2,
    const float* __restrict__ post_g, const float* __restrict__ post_b,
    float* __restrict__ out) {
  const int t = threadIdx.x;
  const int b = blockIdx.x >> 10;
  const int qp = blockIdx.x & 1023;

  __shared__ float sa[128], sz[128], sh[256], red[256];

  if (t < 128) sa[t] = Abuf[((size_t)b * SQL + qp) * 128 + t];
  __syncthreads();

  float z = 0.f;
  if (t < 128) {
    float acc = bp[t];
#pragma unroll 4
    for (int c = 0; c < 128; ++c) acc = fmaf(sa[c], Wp[c * 128 + t], acc);
    acc += skip[((size_t)b * 128 + t) * SQL + qp];
    z = acc;
  }
  // pre-LN
  red[t] = (t < 128) ? z : 0.f;
  __syncthreads();
  for (int s = 128; s > 0; s >>= 1) { if (t < s) red[t] += red[t + s]; __syncthreads(); }
  float mu = red[0] * (1.f / 128.f);
  __syncthreads();
  float dv = (t < 128) ? (z - mu) : 0.f;
  red[t] = dv * dv;
  __syncthreads();
  for (int s = 128; s > 0; s >>= 1) { if (t < s) red[t] += red[t + s]; __syncthreads(); }
  float rstd = rsqrtf(red[0] * (1.f / 128.f) + 1e-5f);
  __syncthreads();
  if (t < 128) sz[t] = (z - mu) * rstd * pre_g[t] + pre_b[t];
  __syncthreads();

  // hidden layer (256 wide), exact GELU
  {
    float acc = b1[t];
#pragma unroll 4
    for (int c = 0; c < 128; ++c) acc = fmaf(sz[c], W1[c * 256 + t], acc);
    sh[t] = 0.5f * acc * (1.f + erff(acc * 0.70710678118654752f));
  }
  __syncthreads();

  float z2 = 0.f;
  if (t < 128) {
    float acc = b2[t];
#pragma unroll 4
    for (int c = 0; c < 256; ++c) acc = fmaf(sh[c], W2[c * 128 + t], acc);
    z2 = sz[t] + acc;
  }
  // post-LN
  red[t] = (t < 128) ? z2 : 0.f;
  __syncthreads();
  for (int s = 128; s > 0; s >>= 1) { if (t < s) red[t] += red[t + s]; __syncthreads(); }
  float mu2 = red[0] * (1.f / 128.f);
  __syncthreads();
  float dv2 = (t < 128) ? (z2 - mu2) : 0.f;
  red[t] = dv2 * dv2;
  __syncthreads();
  for (int s = 128; s > 0; s >>= 1) { if (t < s) red[t] += red[t + s]; __syncthreads(); }
  float rstd2 = rsqrtf(red[0] * (1.f / 128.f) + 1e-5f);
  if (t < 128)
    out[((size_t)b * 128 + t) * SQL + qp] = (z2 - mu2) * rstd2 * post_g[t] + post_b[t];
}

// ---------------------------------------------------------------------------
extern "C" void kernel_launch(void* const* d_in, const int* in_sizes, int n_in,
                              void* d_out, int out_size, void* d_ws, size_t ws_size,
                              hipStream_t stream) {
  const float* q_in   = (const float*)d_in[0];
  const float* k_in   = (const float*)d_in[1];
  const float* v_in   = (const float*)d_in[2];
  const float* skip   = (const float*)d_in[3];
  const float* q_ln_g = (const float*)d_in[4];
  const float* q_ln_b = (const float*)d_in[5];
  const float* Wq     = (const float*)d_in[6];
  const float* bq     = (const float*)d_in[7];
  const float* k_ln_g = (const float*)d_in[8];
  const float* k_ln_b = (const float*)d_in[9];
  const float* Wk     = (const float*)d_in[10];
  const float* bk     = (const float*)d_in[11];
  const float* v_ln_g = (const float*)d_in[12];
  const float* v_ln_b = (const float*)d_in[13];
  const float* Wv     = (const float*)d_in[14];
  const float* bv     = (const float*)d_in[15];
  const float* Wp     = (const float*)d_in[16];
  const float* bp     = (const float*)d_in[17];
  const float* pre_g  = (const float*)d_in[18];
  const float* pre_b  = (const float*)d_in[19];
  const float* W1     = (const float*)d_in[20];
  const float* b1     = (const float*)d_in[21];
  const float* W2     = (const float*)d_in[22];
  const float* b2     = (const float*)d_in[23];
  const float* post_g = (const float*)d_in[24];
  const float* post_b = (const float*)d_in[25];

  // workspace layout (bf16 buffers then fp32 A)
  const size_t QhN = (size_t)BSZ * NHEAD * NCAM * SQL * 32;        // 1,572,864
  const size_t KhN = (size_t)BSZ * NHEAD * NCAM * SKL * 32 + 4096; // pad for tail overread
  const size_t VtN = KhN;
  unsigned short* Qh = (unsigned short*)d_ws;
  unsigned short* Kh = Qh + QhN;
  unsigned short* Vt = Kh + KhN;
  float* Ab = (float*)(Vt + VtN);
  float* out = (float*)d_out;

  const float scale = 0.17677669529663689f;  // 1/sqrt(32), folded into Q

  proj_kernel<<<(BSZ * NCAM * SQL) / 8, 128, 0, stream>>>(q_in, q_ln_g, q_ln_b, Wq, bq, scale, Qh, SQL, 0);
  proj_kernel<<<(BSZ * NCAM * SKL) / 8, 128, 0, stream>>>(k_in, k_ln_g, k_ln_b, Wk, bk, 1.f, Kh, SKL, 0);
  proj_kernel<<<(BSZ * NCAM * SKL) / 8, 128, 0, stream>>>(v_in, v_ln_g, v_ln_b, Wv, bv, 1.f, Vt, SKL, 1);
  attn_mfma<<<BSZ * NHEAD * (SQL / 16), 256, 0, stream>>>(Qh, Kh, Vt, Ab);
  post_kernel<<<BSZ * SQL, 256, 0, stream>>>(Ab, skip, Wp, bp, pre_g, pre_b,
                                             W1, b1, W2, b2, post_g, post_b, out);
}

// Round 3
// 186.642 us; speedup vs baseline: 3.8952x; 1.6018x over previous
//
#include <hip/hip_runtime.h>
#include <math.h>

#define NCAM 6
#define BSZ 2
#define SQL 1024
#define SKL 1680
#define NHEAD 4
#define DHEAD 32
// 1/sqrt(32) * log2(e)  (folded into Q so softmax uses exp2 directly)
#define QSCALE 0.25503494f

typedef unsigned short ushort_t;
typedef unsigned int uint_t;
typedef __attribute__((ext_vector_type(8))) short short8;   // 8 bf16
typedef __attribute__((ext_vector_type(4))) float f32x4;    // MFMA C/D frag

#define MFMA16 __builtin_amdgcn_mfma_f32_16x16x32_bf16

__device__ __forceinline__ ushort_t f2bf(float x) {
  uint_t u = __builtin_bit_cast(uint_t, x);
  u += 0x7FFFu + ((u >> 16) & 1u);   // RNE
  return (ushort_t)(u >> 16);
}

// ---------------------------------------------------------------------------
// prep: fold LN gains into transposed bf16 weights.
//  q/k/v: WT''[out][in] = g[in]*W[in][out], u[out]=colsum(W''), bb=b@W+bias
//  Wp, W2: plain transpose. W1: pre_g folded, b1'' = pre_b@W1 + b1.
// 28 blocks x 256 threads; block = 32 output columns.
// ---------------------------------------------------------------------------
__global__ __launch_bounds__(256) void prep_kernel(
    const float* __restrict__ Wq, const float* __restrict__ qg, const float* __restrict__ qb, const float* __restrict__ bq,
    const float* __restrict__ Wk, const float* __restrict__ kg, const float* __restrict__ kbb, const float* __restrict__ bk,
    const float* __restrict__ Wv, const float* __restrict__ vg, const float* __restrict__ vbb, const float* __restrict__ bv,
    const float* __restrict__ Wp,
    const float* __restrict__ W1, const float* __restrict__ pre_g, const float* __restrict__ pre_b, const float* __restrict__ b1,
    const float* __restrict__ W2,
    ushort_t* WqT, ushort_t* WkT, ushort_t* WvT, ushort_t* WpT, ushort_t* W1T, ushort_t* W2T,
    float* uq, float* bbq, float* uk, float* bbk, float* uv, float* bbv, float* b1p) {
  const int mb = blockIdx.x;
  const float *W, *g = nullptr, *bln = nullptr, *bias = nullptr;
  ushort_t* WT; float *u = nullptr, *bb = nullptr;
  int kin = 128, nout = 128, ob;
  if (mb < 4)       { W=Wq; g=qg; bln=qb;   bias=bq; WT=WqT; u=uq; bb=bbq; ob=mb*32; }
  else if (mb < 8)  { W=Wk; g=kg; bln=kbb;  bias=bk; WT=WkT; u=uk; bb=bbk; ob=(mb-4)*32; }
  else if (mb < 12) { W=Wv; g=vg; bln=vbb;  bias=bv; WT=WvT; u=uv; bb=bbv; ob=(mb-8)*32; }
  else if (mb < 16) { W=Wp; WT=WpT; ob=(mb-12)*32; }
  else if (mb < 24) { W=W1; g=pre_g; bln=pre_b; bias=b1; WT=W1T; bb=b1p; nout=256; ob=(mb-16)*32; }
  else              { W=W2; WT=W2T; kin=256; ob=(mb-24)*32; }
  const int t = threadIdx.x;
  const int oc = t & 31, ig = t >> 5;
  const int out = ob + oc;
  const int nper = kin >> 3;
  float su = 0.f, sb = 0.f;
  for (int j = 0; j < nper; ++j) {
    const int in = ig * nper + j;
    const float wv_ = W[(size_t)in * nout + out];
    const float wg = g ? g[in] * wv_ : wv_;
    WT[(size_t)out * kin + in] = f2bf(wg);
    su += wg;
    if (bln) sb += bln[in] * wv_;
  }
  __shared__ float sU[8][32], sB[8][32];
  sU[ig][oc] = su; sB[ig][oc] = sb;
  __syncthreads();
  if (t < 32) {
    float tu = 0.f, tb = 0.f;
#pragma unroll
    for (int i = 0; i < 8; ++i) { tu += sU[i][t]; tb += sB[i][t]; }
    if (u)  u[ob + t] = tu;
    if (bb) bb[ob + t] = tb + (bias ? bias[ob + t] : 0.f);
  }
}

// ---------------------------------------------------------------------------
// proj: bf16 MFMA GEMM on RAW x (LN folded into epilogue).
// Block = 64 positions x 128 outs, 256 thr / 4 waves (wave = head slab of 32).
// Grid: 192 Q-tiles + 324 K + 324 V.  Q/K out: (bm,cam,pos,32); V: (bm,cam,32,SKL).
// ---------------------------------------------------------------------------
__global__ __launch_bounds__(256) void proj_mfma(
    const float* __restrict__ xq, const float* __restrict__ xk, const float* __restrict__ xv,
    const ushort_t* __restrict__ WqT, const ushort_t* __restrict__ WkT, const ushort_t* __restrict__ WvT,
    const float* __restrict__ uq, const float* __restrict__ uk, const float* __restrict__ uv,
    const float* __restrict__ bbq, const float* __restrict__ bbk, const float* __restrict__ bbv,
    ushort_t* __restrict__ Qh, ushort_t* __restrict__ Kh, ushort_t* __restrict__ Vt) {
  int blk = blockIdx.x;
  const float* x; const ushort_t* WT; const float* u; const float* bb;
  ushort_t* out; int S, ntile, vmode; float oscale;
  if (blk < 192)      { x=xq; WT=WqT; u=uq; bb=bbq; out=Qh; S=SQL; ntile=16; vmode=0; oscale=QSCALE; }
  else if (blk < 516) { blk-=192; x=xk; WT=WkT; u=uk; bb=bbk; out=Kh; S=SKL; ntile=27; vmode=0; oscale=1.f; }
  else                { blk-=516; x=xv; WT=WvT; u=uv; bb=bbv; out=Vt; S=SKL; ntile=27; vmode=1; oscale=1.f; }
  const int bn = blk / ntile;
  const int pos0 = (blk - bn * ntile) * 64;
  int valid = S - pos0; if (valid > 64) valid = 64;   // 64 or 16

  const int t = threadIdx.x;
  __shared__ ushort_t sX[64 * 128];           // [pos][ch], XOR-swizzled 16B chunks
  __shared__ float sS1[4][64], sS2[4][64];
  __shared__ float sMu[64], sRs[64];

  {  // stage + stats: thread = (pos, ch-quarter)
    const int pos = t & 63, qr = t >> 6;
    int lp = pos; if (lp >= valid) lp = valid - 1;   // clamp (no OOB)
    const float* xb = x + ((size_t)bn * 128 + qr * 32) * S + pos0 + lp;
    float v[32]; float s1 = 0.f, s2 = 0.f;
#pragma unroll
    for (int j = 0; j < 32; ++j) { float xv_ = xb[(size_t)j * S]; v[j] = xv_; s1 += xv_; s2 += xv_ * xv_; }
    sS1[qr][pos] = s1; sS2[qr][pos] = s2;
#pragma unroll
    for (int c = 0; c < 4; ++c) {
      short8 pk;
#pragma unroll
      for (int e = 0; e < 8; ++e) pk[e] = (short)f2bf(v[c * 8 + e]);
      const int phys = (qr * 4 + c) ^ (pos & 7);
      *((short8*)&sX[pos * 128 + phys * 8]) = pk;
    }
  }
  __syncthreads();
  if (t < 64) {
    const float a1 = sS1[0][t] + sS1[1][t] + sS1[2][t] + sS1[3][t];
    const float a2 = sS2[0][t] + sS2[1][t] + sS2[2][t] + sS2[3][t];
    const float mu = a1 * (1.f / 128.f);
    sMu[t] = mu; sRs[t] = rsqrtf(a2 * (1.f / 128.f) - mu * mu + 1e-5f);
  }
  __syncthreads();

  const int w = t >> 6, l = t & 63, lq = l & 15, quad = l >> 4;
  short8 af[2][4];
#pragma unroll
  for (int ms = 0; ms < 2; ++ms)
#pragma unroll
    for (int kk = 0; kk < 4; ++kk)
      af[ms][kk] = *((const short8*)(WT + (size_t)(w * 32 + ms * 16 + lq) * 128 + quad * 8 + kk * 32));
  f32x4 acc[4][2];
#pragma unroll
  for (int ns = 0; ns < 4; ++ns)
#pragma unroll
    for (int ms = 0; ms < 2; ++ms) acc[ns][ms] = (f32x4){0.f, 0.f, 0.f, 0.f};
#pragma unroll
  for (int ns = 0; ns < 4; ++ns) {
    short8 bf[4];
#pragma unroll
    for (int kk = 0; kk < 4; ++kk) {
      const int phys = (quad + 4 * kk) ^ (lq & 7);
      bf[kk] = *((const short8*)&sX[(ns * 16 + lq) * 128 + phys * 8]);
    }
#pragma unroll
    for (int ms = 0; ms < 2; ++ms) {
      f32x4 a = acc[ns][ms];
#pragma unroll
      for (int kk = 0; kk < 4; ++kk) a = MFMA16(af[ms][kk], bf[kk], a, 0, 0, 0);
      acc[ns][ms] = a;
    }
  }

  // epilogue: rstd*(acc - mu*u) + bb, scaled; store
  const int b_ = bn / NCAM, cam = bn - b_ * NCAM;
  const size_t slab = (size_t)((b_ * NHEAD + w) * NCAM + cam);
#pragma unroll
  for (int ms = 0; ms < 2; ++ms) {
    float uu[4], bv_[4];
#pragma unroll
    for (int r = 0; r < 4; ++r) {
      const int og = w * 32 + ms * 16 + quad * 4 + r;
      uu[r] = u[og]; bv_[r] = bb[og];
    }
#pragma unroll
    for (int ns = 0; ns < 4; ++ns) {
      const int p = ns * 16 + lq;
      if (p < valid) {
        const float mu = sMu[p], rs = sRs[p];
        float val[4];
#pragma unroll
        for (int r = 0; r < 4; ++r)
          val[r] = ((acc[ns][ms][r] - mu * uu[r]) * rs + bv_[r]) * oscale;
        if (vmode == 0) {
          ushort_t e0 = f2bf(val[0]), e1 = f2bf(val[1]), e2 = f2bf(val[2]), e3 = f2bf(val[3]);
          ushort_t* orow = out + (slab * S + pos0 + p) * 32 + ms * 16 + quad * 4;
          *((uint_t*)orow) = (uint_t)e0 | ((uint_t)e1 << 16);
          *((uint_t*)(orow + 2)) = (uint_t)e2 | ((uint_t)e3 << 16);
        } else {
#pragma unroll
          for (int r = 0; r < 4; ++r)
            out[(slab * 32 + ms * 16 + quad * 4 + r) * (size_t)SKL + pos0 + p] = f2bf(val[r]);
        }
      }
    }
  }
}

// ---------------------------------------------------------------------------
// MFMA flash attention, no-max softmax (logits pre-scaled by log2e; exp2).
// Grid 512 blocks (bm in low 3 bits for XCD L2 locality), 512 thr = 8 waves.
// Wave w: cameras [ (w>>2)*3, +3 ), key quarter w&3 of each camera.
// Output Ab: bf16 (b, pos, 128) already divided by l.
// ---------------------------------------------------------------------------
__global__ __launch_bounds__(512) void attn_mfma(
    const ushort_t* __restrict__ Qh, const ushort_t* __restrict__ Kh,
    const ushort_t* __restrict__ Vt, ushort_t* __restrict__ Ab) {
  const int t = threadIdx.x;
  const int w = t >> 6, l = t & 63;
  const int lq = l & 15, quad = l >> 4;
  const int bm = blockIdx.x & 7;
  const int q0 = (blockIdx.x >> 3) * 16;

  const int camg = w >> 2, kq = w & 3;
  const int kstart = kq * 448;
  const int nfull = (kq == 3) ? 5 : 7;

  __shared__ ushort_t sP[8][16][72];
  __shared__ float sO[8][16][36];
  __shared__ float sL[8][16];

  f32x4 o0 = {0.f, 0.f, 0.f, 0.f};
  f32x4 o1 = {0.f, 0.f, 0.f, 0.f};
  float l_cur = 0.f;

  for (int nc = 0; nc < 3; ++nc) {
    const int n = camg * 3 + nc;
    const ushort_t* Kb = Kh + (size_t)(bm * NCAM + n) * SKL * 32;
    const ushort_t* Vb = Vt + (size_t)(bm * NCAM + n) * 32 * SKL;
    const short8 qf = *((const short8*)(Qh + ((size_t)(bm * NCAM + n) * SQL + q0 + lq) * 32 + quad * 8));

    for (int kt = 0; kt < nfull; ++kt) {
      const int kb = kstart + kt * 64;
      short8 kf[4];
#pragma unroll
      for (int st = 0; st < 4; ++st)
        kf[st] = *((const short8*)(Kb + (size_t)(kb + st * 16 + lq) * 32 + quad * 8));
      const short8 v00 = *((const short8*)(Vb + (size_t)lq * SKL + kb + quad * 8));
      const short8 v01 = *((const short8*)(Vb + (size_t)lq * SKL + kb + 32 + quad * 8));
      const short8 v10 = *((const short8*)(Vb + (size_t)(16 + lq) * SKL + kb + quad * 8));
      const short8 v11 = *((const short8*)(Vb + (size_t)(16 + lq) * SKL + kb + 32 + quad * 8));

      f32x4 s[4];
#pragma unroll
      for (int st = 0; st < 4; ++st) {
        f32x4 z = {0.f, 0.f, 0.f, 0.f};
        s[st] = MFMA16(kf[st], qf, z, 0, 0, 0);
      }
      float ls = 0.f;
#pragma unroll
      for (int st = 0; st < 4; ++st) {
        const float p0 = __builtin_amdgcn_exp2f(s[st][0]);
        const float p1 = __builtin_amdgcn_exp2f(s[st][1]);
        const float p2 = __builtin_amdgcn_exp2f(s[st][2]);
        const float p3 = __builtin_amdgcn_exp2f(s[st][3]);
        ls += (p0 + p1) + (p2 + p3);
        const uint_t pa = __builtin_amdgcn_perm(__builtin_bit_cast(uint_t, p1), __builtin_bit_cast(uint_t, p0), 0x07060302u);
        const uint_t pb = __builtin_amdgcn_perm(__builtin_bit_cast(uint_t, p3), __builtin_bit_cast(uint_t, p2), 0x07060302u);
        *((uint2*)&sP[w][lq][st * 16 + quad * 4]) = make_uint2(pa, pb);
      }
      ls += __shfl_xor(ls, 16, 64);
      ls += __shfl_xor(ls, 32, 64);
      l_cur += ls;

      const short8 pf0 = *((const short8*)&sP[w][lq][quad * 8]);
      const short8 pf1 = *((const short8*)&sP[w][lq][32 + quad * 8]);
      o0 = MFMA16(v00, pf0, o0, 0, 0, 0);
      o1 = MFMA16(v10, pf0, o1, 0, 0, 0);
      o0 = MFMA16(v01, pf1, o0, 0, 0, 0);
      o1 = MFMA16(v11, pf1, o1, 0, 0, 0);
    }

    if (kq == 3) {  // 16-key tail (keys 1664..1679)
      const int kb = kstart + 320;
      const short8 kf = *((const short8*)(Kb + (size_t)(kb + lq) * 32 + quad * 8));
      const short8 v00 = *((const short8*)(Vb + (size_t)lq * SKL + kb + quad * 8));
      const short8 v10 = *((const short8*)(Vb + (size_t)(16 + lq) * SKL + kb + quad * 8));
      f32x4 z = {0.f, 0.f, 0.f, 0.f};
      const f32x4 s0 = MFMA16(kf, qf, z, 0, 0, 0);
      const float p0 = __builtin_amdgcn_exp2f(s0[0]);
      const float p1 = __builtin_amdgcn_exp2f(s0[1]);
      const float p2 = __builtin_amdgcn_exp2f(s0[2]);
      const float p3 = __builtin_amdgcn_exp2f(s0[3]);
      float ls = (p0 + p1) + (p2 + p3);
      const uint_t pa = __builtin_amdgcn_perm(__builtin_bit_cast(uint_t, p1), __builtin_bit_cast(uint_t, p0), 0x07060302u);
      const uint_t pb = __builtin_amdgcn_perm(__builtin_bit_cast(uint_t, p3), __builtin_bit_cast(uint_t, p2), 0x07060302u);
      *((uint2*)&sP[w][lq][quad * 4]) = make_uint2(pa, pb);
      *((uint2*)&sP[w][lq][16 + quad * 4]) = make_uint2(0u, 0u);  // zero keys 16..31
      ls += __shfl_xor(ls, 16, 64);
      ls += __shfl_xor(ls, 32, 64);
      l_cur += ls;
      const short8 pf0 = *((const short8*)&sP[w][lq][quad * 8]);
      o0 = MFMA16(v00, pf0, o0, 0, 0, 0);
      o1 = MFMA16(v10, pf0, o1, 0, 0, 0);
    }
  }

  // combine 8 partitions (pure sums — no max tracking)
  *((f32x4*)&sO[w][lq][quad * 4]) = o0;
  *((f32x4*)&sO[w][lq][16 + quad * 4]) = o1;
  if (l < 16) sL[w][l] = l_cur;
  __syncthreads();
  if (w == 0) {
    float lf = 0.f;
    f32x4 a0 = {0.f, 0.f, 0.f, 0.f}, a1 = {0.f, 0.f, 0.f, 0.f};
#pragma unroll
    for (int ww = 0; ww < 8; ++ww) {
      lf += sL[ww][lq];
      a0 += *((const f32x4*)&sO[ww][lq][quad * 4]);
      a1 += *((const f32x4*)&sO[ww][lq][16 + quad * 4]);
    }
    const float inv = 1.f / lf;
    const int b = bm >> 2, hm = bm & 3;
    ushort_t* op = Ab + ((size_t)b * SQL + q0 + lq) * 128 + hm * 32 + quad * 4;
    ushort4 w0 = make_ushort4(f2bf(a0[0] * inv), f2bf(a0[1] * inv), f2bf(a0[2] * inv), f2bf(a0[3] * inv));
    ushort4 w1 = make_ushort4(f2bf(a1[0] * inv), f2bf(a1[1] * inv), f2bf(a1[2] * inv), f2bf(a1[3] * inv));
    *((ushort4*)op) = w0;
    *((ushort4*)(op + 16)) = w1;
  }
}

// ---------------------------------------------------------------------------
// post: a@Wp + skip -> preLN -> gelu(n@W1''+b1'')@W2 + res -> postLN -> out.
// Block = 16 positions, 256 thr / 4 waves. Grid 128.
// ---------------------------------------------------------------------------
__global__ __launch_bounds__(256) void post_mfma(
    const ushort_t* __restrict__ Ab, const float* __restrict__ skip,
    const ushort_t* __restrict__ WpT, const float* __restrict__ bp,
    const float* __restrict__ pre_g, const float* __restrict__ pre_b,
    const ushort_t* __restrict__ W1T, const float* __restrict__ b1p,
    const ushort_t* __restrict__ W2T, const float* __restrict__ b2,
    const float* __restrict__ post_g, const float* __restrict__ post_b,
    float* __restrict__ out) {
  const int t = threadIdx.x;
  const int w = t >> 6, l = t & 63, lq = l & 15, quad = l >> 4;
  const int b = blockIdx.x >> 6;
  const int p0 = (blockIdx.x & 63) * 16;

  __shared__ float zf[16 * 132];
  __shared__ float sRes[16 * 132];
  __shared__ ushort_t sZb[16 * 128];
  __shared__ ushort_t sH[16 * 256];
  __shared__ float sMu[16], sRs[16];

  // ---- GEMM1: z = a@Wp ----
  f32x4 z[2] = {{0.f,0.f,0.f,0.f},{0.f,0.f,0.f,0.f}};
#pragma unroll
  for (int kk = 0; kk < 4; ++kk) {
    const short8 bfr = *((const short8*)(Ab + ((size_t)b * SQL + p0 + lq) * 128 + quad * 8 + kk * 32));
#pragma unroll
    for (int ms = 0; ms < 2; ++ms) {
      const short8 afr = *((const short8*)(WpT + (size_t)(w * 32 + ms * 16 + lq) * 128 + quad * 8 + kk * 32));
      z[ms] = MFMA16(afr, bfr, z[ms], 0, 0, 0);
    }
  }
#pragma unroll
  for (int ms = 0; ms < 2; ++ms)
#pragma unroll
    for (int r = 0; r < 4; ++r) {
      const int o = w * 32 + ms * 16 + quad * 4 + r;
      zf[lq * 132 + o] = z[ms][r] + bp[o] + skip[(size_t)b * 131072 + (size_t)o * 1024 + p0 + lq];
    }
  __syncthreads();
  // ---- preLN stats (wave 0) ----
  if (w == 0) {
    const int pos = l & 15, qr = l >> 4;
    float s1 = 0.f, s2 = 0.f;
#pragma unroll
    for (int j = 0; j < 32; ++j) { const float vv = zf[pos * 132 + qr * 32 + j]; s1 += vv; s2 += vv * vv; }
    s1 += __shfl_xor(s1, 16, 64); s1 += __shfl_xor(s1, 32, 64);
    s2 += __shfl_xor(s2, 16, 64); s2 += __shfl_xor(s2, 32, 64);
    const float mu = s1 * (1.f / 128.f);
    if (qr == 0) { sMu[pos] = mu; sRs[pos] = rsqrtf(s2 * (1.f / 128.f) - mu * mu + 1e-5f); }
  }
  __syncthreads();
  // ---- normalize: sZb = bf16(n) (swizzled); sRes = n*g+b ----
  {
    const int pos = t & 15, grp = t >> 4;
    const float mu = sMu[pos], rs = sRs[pos];
    short8 pk;
#pragma unroll
    for (int i = 0; i < 8; ++i) {
      const int ch = grp * 8 + i;
      const float nv = (zf[pos * 132 + ch] - mu) * rs;
      pk[i] = (short)f2bf(nv);
      sRes[pos * 132 + ch] = nv * pre_g[ch] + pre_b[ch];
    }
    *((short8*)&sZb[pos * 128 + (grp ^ (pos & 7)) * 8]) = pk;
  }
  __syncthreads();
  // ---- GEMM2 + exact gelu ----
  f32x4 h[4];
#pragma unroll
  for (int ms = 0; ms < 4; ++ms) h[ms] = (f32x4){0.f, 0.f, 0.f, 0.f};
  short8 bz[4];
#pragma unroll
  for (int kk = 0; kk < 4; ++kk)
    bz[kk] = *((const short8*)&sZb[lq * 128 + ((quad + 4 * kk) ^ (lq & 7)) * 8]);
#pragma unroll
  for (int ms = 0; ms < 4; ++ms)
#pragma unroll
    for (int kk = 0; kk < 4; ++kk) {
      const short8 afr = *((const short8*)(W1T + (size_t)(w * 64 + ms * 16 + lq) * 128 + quad * 8 + kk * 32));
      h[ms] = MFMA16(afr, bz[kk], h[ms], 0, 0, 0);
    }
#pragma unroll
  for (int ms = 0; ms < 4; ++ms)
#pragma unroll
    for (int r = 0; r < 4; ++r) {
      const int o = w * 64 + ms * 16 + quad * 4 + r;
      float hv = h[ms][r] + b1p[o];
      hv = 0.5f * hv * (1.f + erff(hv * 0.70710678118654752f));
      const int phys = (o >> 3) ^ (lq & 7);
      sH[lq * 256 + phys * 8 + (o & 7)] = f2bf(hv);
    }
  __syncthreads();
  // ---- GEMM3 + residual ----
  f32x4 z2[2] = {{0.f,0.f,0.f,0.f},{0.f,0.f,0.f,0.f}};
#pragma unroll
  for (int kk = 0; kk < 8; ++kk) {
    const short8 bh = *((const short8*)&sH[lq * 256 + ((quad + 4 * kk) ^ (lq & 7)) * 8]);
#pragma unroll
    for (int ms = 0; ms < 2; ++ms) {
      const short8 afr = *((const short8*)(W2T + (size_t)(w * 32 + ms * 16 + lq) * 256 + quad * 8 + kk * 32));
      z2[ms] = MFMA16(afr, bh, z2[ms], 0, 0, 0);
    }
  }
  __syncthreads();
#pragma unroll
  for (int ms = 0; ms < 2; ++ms)
#pragma unroll
    for (int r = 0; r < 4; ++r) {
      const int o = w * 32 + ms * 16 + quad * 4 + r;
      zf[lq * 132 + o] = z2[ms][r] + b2[o] + sRes[lq * 132 + o];
    }
  __syncthreads();
  // ---- postLN stats ----
  if (w == 0) {
    const int pos = l & 15, qr = l >> 4;
    float s1 = 0.f, s2 = 0.f;
#pragma unroll
    for (int j = 0; j < 32; ++j) { const float vv = zf[pos * 132 + qr * 32 + j]; s1 += vv; s2 += vv * vv; }
    s1 += __shfl_xor(s1, 16, 64); s1 += __shfl_xor(s1, 32, 64);
    s2 += __shfl_xor(s2, 16, 64); s2 += __shfl_xor(s2, 32, 64);
    const float mu = s1 * (1.f / 128.f);
    if (qr == 0) { sMu[pos] = mu; sRs[pos] = rsqrtf(s2 * (1.f / 128.f) - mu * mu + 1e-5f); }
  }
  __syncthreads();
  // ---- final write (b, 128, 1024) ----
  {
    const int pos = t & 15, grp = t >> 4;
    const float mu = sMu[pos], rs = sRs[pos];
#pragma unroll
    for (int i = 0; i < 8; ++i) {
      const int ch = grp * 8 + i;
      out[(size_t)b * 131072 + (size_t)ch * 1024 + p0 + pos] =
          (zf[pos * 132 + ch] - mu) * rs * post_g[ch] + post_b[ch];
    }
  }
}

// ---------------------------------------------------------------------------
extern "C" void kernel_launch(void* const* d_in, const int* in_sizes, int n_in,
                              void* d_out, int out_size, void* d_ws, size_t ws_size,
                              hipStream_t stream) {
  const float* q_in   = (const float*)d_in[0];
  const float* k_in   = (const float*)d_in[1];
  const float* v_in   = (const float*)d_in[2];
  const float* skip   = (const float*)d_in[3];
  const float* q_ln_g = (const float*)d_in[4];
  const float* q_ln_b = (const float*)d_in[5];
  const float* Wq     = (const float*)d_in[6];
  const float* bq     = (const float*)d_in[7];
  const float* k_ln_g = (const float*)d_in[8];
  const float* k_ln_b = (const float*)d_in[9];
  const float* Wk     = (const float*)d_in[10];
  const float* bk     = (const float*)d_in[11];
  const float* v_ln_g = (const float*)d_in[12];
  const float* v_ln_b = (const float*)d_in[13];
  const float* Wv     = (const float*)d_in[14];
  const float* bv     = (const float*)d_in[15];
  const float* Wp     = (const float*)d_in[16];
  const float* bp     = (const float*)d_in[17];
  const float* pre_g  = (const float*)d_in[18];
  const float* pre_b  = (const float*)d_in[19];
  const float* W1     = (const float*)d_in[20];
  const float* b1     = (const float*)d_in[21];
  const float* W2     = (const float*)d_in[22];
  const float* b2     = (const float*)d_in[23];
  const float* post_g = (const float*)d_in[24];
  const float* post_b = (const float*)d_in[25];

  char* base = (char*)d_ws;
  ushort_t* WqT = (ushort_t*)base; base += 16384 * 2;
  ushort_t* WkT = (ushort_t*)base; base += 16384 * 2;
  ushort_t* WvT = (ushort_t*)base; base += 16384 * 2;
  ushort_t* WpT = (ushort_t*)base; base += 16384 * 2;
  ushort_t* W1T = (ushort_t*)base; base += 32768 * 2;
  ushort_t* W2T = (ushort_t*)base; base += 32768 * 2;
  float* uq  = (float*)base; base += 128 * 4;
  float* bbq = (float*)base; base += 128 * 4;
  float* uk  = (float*)base; base += 128 * 4;
  float* bbk = (float*)base; base += 128 * 4;
  float* uv  = (float*)base; base += 128 * 4;
  float* bbv = (float*)base; base += 128 * 4;
  float* b1p = (float*)base; base += 256 * 4;
  base = (char*)(((size_t)base + 255) & ~(size_t)255);
  ushort_t* Qh = (ushort_t*)base; base += (size_t)1572864 * 2;
  ushort_t* Kh = (ushort_t*)base; base += (size_t)(2580480 + 4096) * 2;
  ushort_t* Vt = (ushort_t*)base; base += (size_t)(2580480 + 4096) * 2;
  ushort_t* Ab = (ushort_t*)base; base += (size_t)262144 * 2;
  float* out = (float*)d_out;

  prep_kernel<<<28, 256, 0, stream>>>(
      Wq, q_ln_g, q_ln_b, bq, Wk, k_ln_g, k_ln_b, bk, Wv, v_ln_g, v_ln_b, bv,
      Wp, W1, pre_g, pre_b, b1, W2,
      WqT, WkT, WvT, WpT, W1T, W2T, uq, bbq, uk, bbk, uv, bbv, b1p);
  proj_mfma<<<840, 256, 0, stream>>>(
      q_in, k_in, v_in, WqT, WkT, WvT, uq, uk, uv, bbq, bbk, bbv, Qh, Kh, Vt);
  attn_mfma<<<512, 512, 0, stream>>>(Qh, Kh, Vt, Ab);
  post_mfma<<<128, 256, 0, stream>>>(
      Ab, skip, WpT, bp, pre_g, pre_b, W1T, b1p, W2T, b2, post_g, post_b, out);
}

// Round 4
// 184.485 us; speedup vs baseline: 3.9407x; 1.0117x over previous
//
#include <hip/hip_runtime.h>
#include <math.h>

#define NCAM 6
#define BSZ 2
#define SQL 1024
#define SKL 1680
#define NHEAD 4
#define DHEAD 32
// 1/sqrt(32) * log2(e)  (folded into Q so softmax uses exp2 directly)
#define QSCALE 0.25503494f

typedef unsigned short ushort_t;
typedef unsigned int uint_t;
typedef __attribute__((ext_vector_type(8))) short short8;   // 8 bf16
typedef __attribute__((ext_vector_type(4))) float f32x4;    // MFMA C/D frag

#define MFMA16 __builtin_amdgcn_mfma_f32_16x16x32_bf16

__device__ __forceinline__ ushort_t f2bf(float x) {
  uint_t u = __builtin_bit_cast(uint_t, x);
  u += 0x7FFFu + ((u >> 16) & 1u);   // RNE
  return (ushort_t)(u >> 16);
}

// exact-grade GELU: erf via Abramowitz-Stegun 7.1.26 (|err|<=1.5e-7)
__device__ __forceinline__ float fast_gelu(float x) {
  const float ax = fabsf(x) * 0.70710678118654752f;
  const float tt = __builtin_amdgcn_rcpf(fmaf(0.3275911f, ax, 1.f));
  float poly = fmaf(tt, 1.061405429f, -1.453152027f);
  poly = fmaf(tt, poly, 1.421413741f);
  poly = fmaf(tt, poly, -0.284496736f);
  poly = fmaf(tt, poly, 0.254829592f);
  poly *= tt;
  const float e = __builtin_amdgcn_exp2f(-ax * ax * 1.4426950408889634f);
  float er = fmaf(-poly, e, 1.f);
  er = copysignf(er, x);
  return 0.5f * x * (1.f + er);
}

// ---------------------------------------------------------------------------
// prep: fold LN gains into transposed bf16 weights.
// ---------------------------------------------------------------------------
__global__ __launch_bounds__(256) void prep_kernel(
    const float* __restrict__ Wq, const float* __restrict__ qg, const float* __restrict__ qb, const float* __restrict__ bq,
    const float* __restrict__ Wk, const float* __restrict__ kg, const float* __restrict__ kbb, const float* __restrict__ bk,
    const float* __restrict__ Wv, const float* __restrict__ vg, const float* __restrict__ vbb, const float* __restrict__ bv,
    const float* __restrict__ Wp,
    const float* __restrict__ W1, const float* __restrict__ pre_g, const float* __restrict__ pre_b, const float* __restrict__ b1,
    const float* __restrict__ W2,
    ushort_t* WqT, ushort_t* WkT, ushort_t* WvT, ushort_t* WpT, ushort_t* W1T, ushort_t* W2T,
    float* uq, float* bbq, float* uk, float* bbk, float* uv, float* bbv, float* b1p) {
  const int mb = blockIdx.x;
  const float *W, *g = nullptr, *bln = nullptr, *bias = nullptr;
  ushort_t* WT; float *u = nullptr, *bb = nullptr;
  int kin = 128, nout = 128, ob;
  if (mb < 4)       { W=Wq; g=qg; bln=qb;   bias=bq; WT=WqT; u=uq; bb=bbq; ob=mb*32; }
  else if (mb < 8)  { W=Wk; g=kg; bln=kbb;  bias=bk; WT=WkT; u=uk; bb=bbk; ob=(mb-4)*32; }
  else if (mb < 12) { W=Wv; g=vg; bln=vbb;  bias=bv; WT=WvT; u=uv; bb=bbv; ob=(mb-8)*32; }
  else if (mb < 16) { W=Wp; WT=WpT; ob=(mb-12)*32; }
  else if (mb < 24) { W=W1; g=pre_g; bln=pre_b; bias=b1; WT=W1T; bb=b1p; nout=256; ob=(mb-16)*32; }
  else              { W=W2; WT=W2T; kin=256; ob=(mb-24)*32; }
  const int t = threadIdx.x;
  const int oc = t & 31, ig = t >> 5;
  const int out = ob + oc;
  const int nper = kin >> 3;
  float su = 0.f, sb = 0.f;
  for (int j = 0; j < nper; ++j) {
    const int in = ig * nper + j;
    const float wv_ = W[(size_t)in * nout + out];
    const float wg = g ? g[in] * wv_ : wv_;
    WT[(size_t)out * kin + in] = f2bf(wg);
    su += wg;
    if (bln) sb += bln[in] * wv_;
  }
  __shared__ float sU[8][32], sB[8][32];
  sU[ig][oc] = su; sB[ig][oc] = sb;
  __syncthreads();
  if (t < 32) {
    float tu = 0.f, tb = 0.f;
#pragma unroll
    for (int i = 0; i < 8; ++i) { tu += sU[i][t]; tb += sB[i][t]; }
    if (u)  u[ob + t] = tu;
    if (bb) bb[ob + t] = tb + (bias ? bias[ob + t] : 0.f);
  }
}

// ---------------------------------------------------------------------------
// proj: bf16 MFMA GEMM on RAW x (LN folded into epilogue).
// ---------------------------------------------------------------------------
__global__ __launch_bounds__(256) void proj_mfma(
    const float* __restrict__ xq, const float* __restrict__ xk, const float* __restrict__ xv,
    const ushort_t* __restrict__ WqT, const ushort_t* __restrict__ WkT, const ushort_t* __restrict__ WvT,
    const float* __restrict__ uq, const float* __restrict__ uk, const float* __restrict__ uv,
    const float* __restrict__ bbq, const float* __restrict__ bbk, const float* __restrict__ bbv,
    ushort_t* __restrict__ Qh, ushort_t* __restrict__ Kh, ushort_t* __restrict__ Vt) {
  int blk = blockIdx.x;
  const float* x; const ushort_t* WT; const float* u; const float* bb;
  ushort_t* out; int S, ntile, vmode; float oscale;
  if (blk < 192)      { x=xq; WT=WqT; u=uq; bb=bbq; out=Qh; S=SQL; ntile=16; vmode=0; oscale=QSCALE; }
  else if (blk < 516) { blk-=192; x=xk; WT=WkT; u=uk; bb=bbk; out=Kh; S=SKL; ntile=27; vmode=0; oscale=1.f; }
  else                { blk-=516; x=xv; WT=WvT; u=uv; bb=bbv; out=Vt; S=SKL; ntile=27; vmode=1; oscale=1.f; }
  const int bn = blk / ntile;
  const int pos0 = (blk - bn * ntile) * 64;
  int valid = S - pos0; if (valid > 64) valid = 64;

  const int t = threadIdx.x;
  __shared__ ushort_t sX[64 * 128];
  __shared__ float sS1[4][64], sS2[4][64];
  __shared__ float sMu[64], sRs[64];

  {
    const int pos = t & 63, qr = t >> 6;
    int lp = pos; if (lp >= valid) lp = valid - 1;
    const float* xb = x + ((size_t)bn * 128 + qr * 32) * S + pos0 + lp;
    float v[32]; float s1 = 0.f, s2 = 0.f;
#pragma unroll
    for (int j = 0; j < 32; ++j) { float xv_ = xb[(size_t)j * S]; v[j] = xv_; s1 += xv_; s2 += xv_ * xv_; }
    sS1[qr][pos] = s1; sS2[qr][pos] = s2;
#pragma unroll
    for (int c = 0; c < 4; ++c) {
      short8 pk;
#pragma unroll
      for (int e = 0; e < 8; ++e) pk[e] = (short)f2bf(v[c * 8 + e]);
      const int phys = (qr * 4 + c) ^ (pos & 7);
      *((short8*)&sX[pos * 128 + phys * 8]) = pk;
    }
  }
  __syncthreads();
  if (t < 64) {
    const float a1 = sS1[0][t] + sS1[1][t] + sS1[2][t] + sS1[3][t];
    const float a2 = sS2[0][t] + sS2[1][t] + sS2[2][t] + sS2[3][t];
    const float mu = a1 * (1.f / 128.f);
    sMu[t] = mu; sRs[t] = rsqrtf(a2 * (1.f / 128.f) - mu * mu + 1e-5f);
  }
  __syncthreads();

  const int w = t >> 6, l = t & 63, lq = l & 15, quad = l >> 4;
  short8 af[2][4];
#pragma unroll
  for (int ms = 0; ms < 2; ++ms)
#pragma unroll
    for (int kk = 0; kk < 4; ++kk)
      af[ms][kk] = *((const short8*)(WT + (size_t)(w * 32 + ms * 16 + lq) * 128 + quad * 8 + kk * 32));
  f32x4 acc[4][2];
#pragma unroll
  for (int ns = 0; ns < 4; ++ns)
#pragma unroll
    for (int ms = 0; ms < 2; ++ms) acc[ns][ms] = (f32x4){0.f, 0.f, 0.f, 0.f};
#pragma unroll
  for (int ns = 0; ns < 4; ++ns) {
    short8 bf[4];
#pragma unroll
    for (int kk = 0; kk < 4; ++kk) {
      const int phys = (quad + 4 * kk) ^ (lq & 7);
      bf[kk] = *((const short8*)&sX[(ns * 16 + lq) * 128 + phys * 8]);
    }
#pragma unroll
    for (int ms = 0; ms < 2; ++ms) {
      f32x4 a = acc[ns][ms];
#pragma unroll
      for (int kk = 0; kk < 4; ++kk) a = MFMA16(af[ms][kk], bf[kk], a, 0, 0, 0);
      acc[ns][ms] = a;
    }
  }

  const int b_ = bn / NCAM, cam = bn - b_ * NCAM;
  const size_t slab = (size_t)((b_ * NHEAD + w) * NCAM + cam);
#pragma unroll
  for (int ms = 0; ms < 2; ++ms) {
    float uu[4], bv_[4];
#pragma unroll
    for (int r = 0; r < 4; ++r) {
      const int og = w * 32 + ms * 16 + quad * 4 + r;
      uu[r] = u[og]; bv_[r] = bb[og];
    }
#pragma unroll
    for (int ns = 0; ns < 4; ++ns) {
      const int p = ns * 16 + lq;
      if (p < valid) {
        const float mu = sMu[p], rs = sRs[p];
        float val[4];
#pragma unroll
        for (int r = 0; r < 4; ++r)
          val[r] = ((acc[ns][ms][r] - mu * uu[r]) * rs + bv_[r]) * oscale;
        if (vmode == 0) {
          ushort_t e0 = f2bf(val[0]), e1 = f2bf(val[1]), e2 = f2bf(val[2]), e3 = f2bf(val[3]);
          ushort_t* orow = out + (slab * S + pos0 + p) * 32 + ms * 16 + quad * 4;
          *((uint_t*)orow) = (uint_t)e0 | ((uint_t)e1 << 16);
          *((uint_t*)(orow + 2)) = (uint_t)e2 | ((uint_t)e3 << 16);
        } else {
#pragma unroll
          for (int r = 0; r < 4; ++r)
            out[(slab * 32 + ms * 16 + quad * 4 + r) * (size_t)SKL + pos0 + p] = f2bf(val[r]);
        }
      }
    }
  }
}

// ---------------------------------------------------------------------------
// MFMA flash attention, no-max softmax (exp2; scale folded into Q).
// Grid 256 blocks (bm in low 3 bits -> XCD L2 locality), 1024 thr = 16 waves.
// Block covers 32 queries. Wave w: q-group (w>>3), cam-triple ((w&7)>>2),
// key-quarter (w&3). 16 waves/CU = 4/SIMD; K+V read ONCE per 32 queries
// (halves per-XCD L2 traffic vs the 16-query version).
// ---------------------------------------------------------------------------
__global__ __launch_bounds__(1024, 4) void attn_mfma(
    const ushort_t* __restrict__ Qh, const ushort_t* __restrict__ Kh,
    const ushort_t* __restrict__ Vt, ushort_t* __restrict__ Ab) {
  const int t = threadIdx.x;
  const int w = t >> 6, l = t & 63;
  const int lq = l & 15, quad = l >> 4;
  const int bm = blockIdx.x & 7;
  const int qg = w >> 3;
  const int q0 = (blockIdx.x >> 3) * 32 + qg * 16;
  const int kgrp = w & 7;
  const int camg = kgrp >> 2, kq = kgrp & 3;
  const int kstart = kq * 448;
  const int nfull = (kq == 3) ? 5 : 7;

  __shared__ ushort_t sP[16][16][72];
  __shared__ float sO[16][16][36];
  __shared__ float sL[16][16];

  f32x4 o0 = {0.f, 0.f, 0.f, 0.f};
  f32x4 o1 = {0.f, 0.f, 0.f, 0.f};
  float l_cur = 0.f;

  for (int nc = 0; nc < 3; ++nc) {
    const int n = camg * 3 + nc;
    const ushort_t* Kb = Kh + (size_t)(bm * NCAM + n) * SKL * 32;
    const ushort_t* Vb = Vt + (size_t)(bm * NCAM + n) * 32 * SKL;
    const short8 qf = *((const short8*)(Qh + ((size_t)(bm * NCAM + n) * SQL + q0 + lq) * 32 + quad * 8));

    for (int kt = 0; kt < nfull; ++kt) {
      const int kb = kstart + kt * 64;
      short8 kf[4];
#pragma unroll
      for (int st = 0; st < 4; ++st)
        kf[st] = *((const short8*)(Kb + (size_t)(kb + st * 16 + lq) * 32 + quad * 8));
      const short8 v00 = *((const short8*)(Vb + (size_t)lq * SKL + kb + quad * 8));
      const short8 v01 = *((const short8*)(Vb + (size_t)lq * SKL + kb + 32 + quad * 8));
      const short8 v10 = *((const short8*)(Vb + (size_t)(16 + lq) * SKL + kb + quad * 8));
      const short8 v11 = *((const short8*)(Vb + (size_t)(16 + lq) * SKL + kb + 32 + quad * 8));

      f32x4 s[4];
#pragma unroll
      for (int st = 0; st < 4; ++st) {
        f32x4 z = {0.f, 0.f, 0.f, 0.f};
        s[st] = MFMA16(kf[st], qf, z, 0, 0, 0);
      }
      float ls = 0.f;
#pragma unroll
      for (int st = 0; st < 4; ++st) {
        const float p0 = __builtin_amdgcn_exp2f(s[st][0]);
        const float p1 = __builtin_amdgcn_exp2f(s[st][1]);
        const float p2 = __builtin_amdgcn_exp2f(s[st][2]);
        const float p3 = __builtin_amdgcn_exp2f(s[st][3]);
        ls += (p0 + p1) + (p2 + p3);
        const uint_t pa = __builtin_amdgcn_perm(__builtin_bit_cast(uint_t, p1), __builtin_bit_cast(uint_t, p0), 0x07060302u);
        const uint_t pb = __builtin_amdgcn_perm(__builtin_bit_cast(uint_t, p3), __builtin_bit_cast(uint_t, p2), 0x07060302u);
        *((uint2*)&sP[w][lq][st * 16 + quad * 4]) = make_uint2(pa, pb);
      }
      const short8 pf0 = *((const short8*)&sP[w][lq][quad * 8]);
      const short8 pf1 = *((const short8*)&sP[w][lq][32 + quad * 8]);
      o0 = MFMA16(v00, pf0, o0, 0, 0, 0);
      o1 = MFMA16(v10, pf0, o1, 0, 0, 0);
      o0 = MFMA16(v01, pf1, o0, 0, 0, 0);
      o1 = MFMA16(v11, pf1, o1, 0, 0, 0);
      ls += __shfl_xor(ls, 16, 64);
      ls += __shfl_xor(ls, 32, 64);
      l_cur += ls;
    }

    if (kq == 3) {  // 16-key tail (keys 1664..1679)
      const int kb = kstart + 320;
      const short8 kf = *((const short8*)(Kb + (size_t)(kb + lq) * 32 + quad * 8));
      const short8 v00 = *((const short8*)(Vb + (size_t)lq * SKL + kb + quad * 8));
      const short8 v10 = *((const short8*)(Vb + (size_t)(16 + lq) * SKL + kb + quad * 8));
      f32x4 z = {0.f, 0.f, 0.f, 0.f};
      const f32x4 s0 = MFMA16(kf, qf, z, 0, 0, 0);
      const float p0 = __builtin_amdgcn_exp2f(s0[0]);
      const float p1 = __builtin_amdgcn_exp2f(s0[1]);
      const float p2 = __builtin_amdgcn_exp2f(s0[2]);
      const float p3 = __builtin_amdgcn_exp2f(s0[3]);
      float ls = (p0 + p1) + (p2 + p3);
      const uint_t pa = __builtin_amdgcn_perm(__builtin_bit_cast(uint_t, p1), __builtin_bit_cast(uint_t, p0), 0x07060302u);
      const uint_t pb = __builtin_amdgcn_perm(__builtin_bit_cast(uint_t, p3), __builtin_bit_cast(uint_t, p2), 0x07060302u);
      *((uint2*)&sP[w][lq][quad * 4]) = make_uint2(pa, pb);
      *((uint2*)&sP[w][lq][16 + quad * 4]) = make_uint2(0u, 0u);
      const short8 pf0 = *((const short8*)&sP[w][lq][quad * 8]);
      o0 = MFMA16(v00, pf0, o0, 0, 0, 0);
      o1 = MFMA16(v10, pf0, o1, 0, 0, 0);
      ls += __shfl_xor(ls, 16, 64);
      ls += __shfl_xor(ls, 32, 64);
      l_cur += ls;
    }
  }

  // combine 8 key-partitions per q-group (pure sums — no max tracking)
  *((f32x4*)&sO[w][lq][quad * 4]) = o0;
  *((f32x4*)&sO[w][lq][16 + quad * 4]) = o1;
  if (l < 16) sL[w][l] = l_cur;
  __syncthreads();
  if (kgrp == 0) {
    float lf = 0.f;
    f32x4 a0 = {0.f, 0.f, 0.f, 0.f}, a1 = {0.f, 0.f, 0.f, 0.f};
#pragma unroll
    for (int w2 = 0; w2 < 8; ++w2) {
      const int ww = qg * 8 + w2;
      lf += sL[ww][lq];
      a0 += *((const f32x4*)&sO[ww][lq][quad * 4]);
      a1 += *((const f32x4*)&sO[ww][lq][16 + quad * 4]);
    }
    const float inv = 1.f / lf;
    const int b = bm >> 2, hm = bm & 3;
    ushort_t* op = Ab + ((size_t)b * SQL + q0 + lq) * 128 + hm * 32 + quad * 4;
    ushort4 w0 = make_ushort4(f2bf(a0[0] * inv), f2bf(a0[1] * inv), f2bf(a0[2] * inv), f2bf(a0[3] * inv));
    ushort4 w1 = make_ushort4(f2bf(a1[0] * inv), f2bf(a1[1] * inv), f2bf(a1[2] * inv), f2bf(a1[3] * inv));
    *((ushort4*)op) = w0;
    *((ushort4*)(op + 16)) = w1;
  }
}

// ---------------------------------------------------------------------------
// post: a@Wp + skip -> preLN -> gelu(n@W1''+b1'')@W2 + res -> postLN -> out.
// ---------------------------------------------------------------------------
__global__ __launch_bounds__(256) void post_mfma(
    const ushort_t* __restrict__ Ab, const float* __restrict__ skip,
    const ushort_t* __restrict__ WpT, const float* __restrict__ bp,
    const float* __restrict__ pre_g, const float* __restrict__ pre_b,
    const ushort_t* __restrict__ W1T, const float* __restrict__ b1p,
    const ushort_t* __restrict__ W2T, const float* __restrict__ b2,
    const float* __restrict__ post_g, const float* __restrict__ post_b,
    float* __restrict__ out) {
  const int t = threadIdx.x;
  const int w = t >> 6, l = t & 63, lq = l & 15, quad = l >> 4;
  const int b = blockIdx.x >> 6;
  const int p0 = (blockIdx.x & 63) * 16;

  __shared__ float zf[16 * 132];
  __shared__ float sRes[16 * 132];
  __shared__ ushort_t sZb[16 * 128];
  __shared__ ushort_t sH[16 * 256];
  __shared__ float sMu[16], sRs[16];

  // ---- GEMM1: z = a@Wp ----
  f32x4 z[2] = {{0.f,0.f,0.f,0.f},{0.f,0.f,0.f,0.f}};
#pragma unroll
  for (int kk = 0; kk < 4; ++kk) {
    const short8 bfr = *((const short8*)(Ab + ((size_t)b * SQL + p0 + lq) * 128 + quad * 8 + kk * 32));
#pragma unroll
    for (int ms = 0; ms < 2; ++ms) {
      const short8 afr = *((const short8*)(WpT + (size_t)(w * 32 + ms * 16 + lq) * 128 + quad * 8 + kk * 32));
      z[ms] = MFMA16(afr, bfr, z[ms], 0, 0, 0);
    }
  }
#pragma unroll
  for (int ms = 0; ms < 2; ++ms)
#pragma unroll
    for (int r = 0; r < 4; ++r) {
      const int o = w * 32 + ms * 16 + quad * 4 + r;
      zf[lq * 132 + o] = z[ms][r] + bp[o] + skip[(size_t)b * 131072 + (size_t)o * 1024 + p0 + lq];
    }
  __syncthreads();
  if (w == 0) {
    const int pos = l & 15, qr = l >> 4;
    float s1 = 0.f, s2 = 0.f;
#pragma unroll
    for (int j = 0; j < 32; ++j) { const float vv = zf[pos * 132 + qr * 32 + j]; s1 += vv; s2 += vv * vv; }
    s1 += __shfl_xor(s1, 16, 64); s1 += __shfl_xor(s1, 32, 64);
    s2 += __shfl_xor(s2, 16, 64); s2 += __shfl_xor(s2, 32, 64);
    const float mu = s1 * (1.f / 128.f);
    if (qr == 0) { sMu[pos] = mu; sRs[pos] = rsqrtf(s2 * (1.f / 128.f) - mu * mu + 1e-5f); }
  }
  __syncthreads();
  {
    const int pos = t & 15, grp = t >> 4;
    const float mu = sMu[pos], rs = sRs[pos];
    short8 pk;
#pragma unroll
    for (int i = 0; i < 8; ++i) {
      const int ch = grp * 8 + i;
      const float nv = (zf[pos * 132 + ch] - mu) * rs;
      pk[i] = (short)f2bf(nv);
      sRes[pos * 132 + ch] = nv * pre_g[ch] + pre_b[ch];
    }
    *((short8*)&sZb[pos * 128 + (grp ^ (pos & 7)) * 8]) = pk;
  }
  __syncthreads();
  // ---- GEMM2 + gelu ----
  f32x4 h[4];
#pragma unroll
  for (int ms = 0; ms < 4; ++ms) h[ms] = (f32x4){0.f, 0.f, 0.f, 0.f};
  short8 bz[4];
#pragma unroll
  for (int kk = 0; kk < 4; ++kk)
    bz[kk] = *((const short8*)&sZb[lq * 128 + ((quad + 4 * kk) ^ (lq & 7)) * 8]);
#pragma unroll
  for (int ms = 0; ms < 4; ++ms)
#pragma unroll
    for (int kk = 0; kk < 4; ++kk) {
      const short8 afr = *((const short8*)(W1T + (size_t)(w * 64 + ms * 16 + lq) * 128 + quad * 8 + kk * 32));
      h[ms] = MFMA16(afr, bz[kk], h[ms], 0, 0, 0);
    }
#pragma unroll
  for (int ms = 0; ms < 4; ++ms)
#pragma unroll
    for (int r = 0; r < 4; ++r) {
      const int o = w * 64 + ms * 16 + quad * 4 + r;
      const float hv = fast_gelu(h[ms][r] + b1p[o]);
      const int phys = (o >> 3) ^ (lq & 7);
      sH[lq * 256 + phys * 8 + (o & 7)] = f2bf(hv);
    }
  __syncthreads();
  // ---- GEMM3 + residual ----
  f32x4 z2[2] = {{0.f,0.f,0.f,0.f},{0.f,0.f,0.f,0.f}};
#pragma unroll
  for (int kk = 0; kk < 8; ++kk) {
    const short8 bh = *((const short8*)&sH[lq * 256 + ((quad + 4 * kk) ^ (lq & 7)) * 8]);
#pragma unroll
    for (int ms = 0; ms < 2; ++ms) {
      const short8 afr = *((const short8*)(W2T + (size_t)(w * 32 + ms * 16 + lq) * 256 + quad * 8 + kk * 32));
      z2[ms] = MFMA16(afr, bh, z2[ms], 0, 0, 0);
    }
  }
  __syncthreads();
#pragma unroll
  for (int ms = 0; ms < 2; ++ms)
#pragma unroll
    for (int r = 0; r < 4; ++r) {
      const int o = w * 32 + ms * 16 + quad * 4 + r;
      zf[lq * 132 + o] = z2[ms][r] + b2[o] + sRes[lq * 132 + o];
    }
  __syncthreads();
  if (w == 0) {
    const int pos = l & 15, qr = l >> 4;
    float s1 = 0.f, s2 = 0.f;
#pragma unroll
    for (int j = 0; j < 32; ++j) { const float vv = zf[pos * 132 + qr * 32 + j]; s1 += vv; s2 += vv * vv; }
    s1 += __shfl_xor(s1, 16, 64); s1 += __shfl_xor(s1, 32, 64);
    s2 += __shfl_xor(s2, 16, 64); s2 += __shfl_xor(s2, 32, 64);
    const float mu = s1 * (1.f / 128.f);
    if (qr == 0) { sMu[pos] = mu; sRs[pos] = rsqrtf(s2 * (1.f / 128.f) - mu * mu + 1e-5f); }
  }
  __syncthreads();
  {
    const int pos = t & 15, grp = t >> 4;
    const float mu = sMu[pos], rs = sRs[pos];
#pragma unroll
    for (int i = 0; i < 8; ++i) {
      const int ch = grp * 8 + i;
      out[(size_t)b * 131072 + (size_t)ch * 1024 + p0 + pos] =
          (zf[pos * 132 + ch] - mu) * rs * post_g[ch] + post_b[ch];
    }
  }
}

// ---------------------------------------------------------------------------
extern "C" void kernel_launch(void* const* d_in, const int* in_sizes, int n_in,
                              void* d_out, int out_size, void* d_ws, size_t ws_size,
                              hipStream_t stream) {
  const float* q_in   = (const float*)d_in[0];
  const float* k_in   = (const float*)d_in[1];
  const float* v_in   = (const float*)d_in[2];
  const float* skip   = (const float*)d_in[3];
  const float* q_ln_g = (const float*)d_in[4];
  const float* q_ln_b = (const float*)d_in[5];
  const float* Wq     = (const float*)d_in[6];
  const float* bq     = (const float*)d_in[7];
  const float* k_ln_g = (const float*)d_in[8];
  const float* k_ln_b = (const float*)d_in[9];
  const float* Wk     = (const float*)d_in[10];
  const float* bk     = (const float*)d_in[11];
  const float* v_ln_g = (const float*)d_in[12];
  const float* v_ln_b = (const float*)d_in[13];
  const float* Wv     = (const float*)d_in[14];
  const float* bv     = (const float*)d_in[15];
  const float* Wp     = (const float*)d_in[16];
  const float* bp     = (const float*)d_in[17];
  const float* pre_g  = (const float*)d_in[18];
  const float* pre_b  = (const float*)d_in[19];
  const float* W1     = (const float*)d_in[20];
  const float* b1     = (const float*)d_in[21];
  const float* W2     = (const float*)d_in[22];
  const float* b2     = (const float*)d_in[23];
  const float* post_g = (const float*)d_in[24];
  const float* post_b = (const float*)d_in[25];

  char* base = (char*)d_ws;
  ushort_t* WqT = (ushort_t*)base; base += 16384 * 2;
  ushort_t* WkT = (ushort_t*)base; base += 16384 * 2;
  ushort_t* WvT = (ushort_t*)base; base += 16384 * 2;
  ushort_t* WpT = (ushort_t*)base; base += 16384 * 2;
  ushort_t* W1T = (ushort_t*)base; base += 32768 * 2;
  ushort_t* W2T = (ushort_t*)base; base += 32768 * 2;
  float* uq  = (float*)base; base += 128 * 4;
  float* bbq = (float*)base; base += 128 * 4;
  float* uk  = (float*)base; base += 128 * 4;
  float* bbk = (float*)base; base += 128 * 4;
  float* uv  = (float*)base; base += 128 * 4;
  float* bbv = (float*)base; base += 128 * 4;
  float* b1p = (float*)base; base += 256 * 4;
  base = (char*)(((size_t)base + 255) & ~(size_t)255);
  ushort_t* Qh = (ushort_t*)base; base += (size_t)1572864 * 2;
  ushort_t* Kh = (ushort_t*)base; base += (size_t)(2580480 + 4096) * 2;
  ushort_t* Vt = (ushort_t*)base; base += (size_t)(2580480 + 4096) * 2;
  ushort_t* Ab = (ushort_t*)base; base += (size_t)262144 * 2;
  float* out = (float*)d_out;

  prep_kernel<<<28, 256, 0, stream>>>(
      Wq, q_ln_g, q_ln_b, bq, Wk, k_ln_g, k_ln_b, bk, Wv, v_ln_g, v_ln_b, bv,
      Wp, W1, pre_g, pre_b, b1, W2,
      WqT, WkT, WvT, WpT, W1T, W2T, uq, bbq, uk, bbk, uv, bbv, b1p);
  proj_mfma<<<840, 256, 0, stream>>>(
      q_in, k_in, v_in, WqT, WkT, WvT, uq, uk, uv, bbq, bbk, bbv, Qh, Kh, Vt);
  attn_mfma<<<256, 1024, 0, stream>>>(Qh, Kh, Vt, Ab);
  post_mfma<<<128, 256, 0, stream>>>(
      Ab, skip, WpT, bp, pre_g, pre_b, W1T, b1p, W2T, b2, post_g, post_b, out);
}

// Round 5
// 174.168 us; speedup vs baseline: 4.1742x; 1.0592x over previous
//
#include <hip/hip_runtime.h>
#include <math.h>

#define NCAM 6
#define BSZ 2
#define SQL 1024
#define SKL 1680
#define NHEAD 4
#define DHEAD 32
// 1/sqrt(32) * log2(e)  (folded into Q so softmax uses exp2 directly)
#define QSCALE 0.25503494f

typedef unsigned short ushort_t;
typedef unsigned int uint_t;
typedef __attribute__((ext_vector_type(8))) short short8;   // 8 bf16
typedef __attribute__((ext_vector_type(4))) float f32x4;    // MFMA C/D frag

#define MFMA16 __builtin_amdgcn_mfma_f32_16x16x32_bf16

__device__ __forceinline__ ushort_t f2bf(float x) {
  uint_t u = __builtin_bit_cast(uint_t, x);
  u += 0x7FFFu + ((u >> 16) & 1u);   // RNE
  return (ushort_t)(u >> 16);
}

// exact-grade GELU: erf via Abramowitz-Stegun 7.1.26 (|err|<=1.5e-7)
__device__ __forceinline__ float fast_gelu(float x) {
  const float ax = fabsf(x) * 0.70710678118654752f;
  const float tt = __builtin_amdgcn_rcpf(fmaf(0.3275911f, ax, 1.f));
  float poly = fmaf(tt, 1.061405429f, -1.453152027f);
  poly = fmaf(tt, poly, 1.421413741f);
  poly = fmaf(tt, poly, -0.284496736f);
  poly = fmaf(tt, poly, 0.254829592f);
  poly *= tt;
  const float e = __builtin_amdgcn_exp2f(-ax * ax * 1.4426950408889634f);
  float er = fmaf(-poly, e, 1.f);
  er = copysignf(er, x);
  return 0.5f * x * (1.f + er);
}

// ---------------------------------------------------------------------------
// prep: fold LN gains into transposed bf16 weights.
// ---------------------------------------------------------------------------
__global__ __launch_bounds__(256) void prep_kernel(
    const float* __restrict__ Wq, const float* __restrict__ qg, const float* __restrict__ qb, const float* __restrict__ bq,
    const float* __restrict__ Wk, const float* __restrict__ kg, const float* __restrict__ kbb, const float* __restrict__ bk,
    const float* __restrict__ Wv, const float* __restrict__ vg, const float* __restrict__ vbb, const float* __restrict__ bv,
    const float* __restrict__ Wp,
    const float* __restrict__ W1, const float* __restrict__ pre_g, const float* __restrict__ pre_b, const float* __restrict__ b1,
    const float* __restrict__ W2,
    ushort_t* WqT, ushort_t* WkT, ushort_t* WvT, ushort_t* WpT, ushort_t* W1T, ushort_t* W2T,
    float* uq, float* bbq, float* uk, float* bbk, float* uv, float* bbv, float* b1p) {
  const int mb = blockIdx.x;
  const float *W, *g = nullptr, *bln = nullptr, *bias = nullptr;
  ushort_t* WT; float *u = nullptr, *bb = nullptr;
  int kin = 128, nout = 128, ob;
  if (mb < 4)       { W=Wq; g=qg; bln=qb;   bias=bq; WT=WqT; u=uq; bb=bbq; ob=mb*32; }
  else if (mb < 8)  { W=Wk; g=kg; bln=kbb;  bias=bk; WT=WkT; u=uk; bb=bbk; ob=(mb-4)*32; }
  else if (mb < 12) { W=Wv; g=vg; bln=vbb;  bias=bv; WT=WvT; u=uv; bb=bbv; ob=(mb-8)*32; }
  else if (mb < 16) { W=Wp; WT=WpT; ob=(mb-12)*32; }
  else if (mb < 24) { W=W1; g=pre_g; bln=pre_b; bias=b1; WT=W1T; bb=b1p; nout=256; ob=(mb-16)*32; }
  else              { W=W2; WT=W2T; kin=256; ob=(mb-24)*32; }
  const int t = threadIdx.x;
  const int oc = t & 31, ig = t >> 5;
  const int out = ob + oc;
  const int nper = kin >> 3;
  float su = 0.f, sb = 0.f;
  for (int j = 0; j < nper; ++j) {
    const int in = ig * nper + j;
    const float wv_ = W[(size_t)in * nout + out];
    const float wg = g ? g[in] * wv_ : wv_;
    WT[(size_t)out * kin + in] = f2bf(wg);
    su += wg;
    if (bln) sb += bln[in] * wv_;
  }
  __shared__ float sU[8][32], sB[8][32];
  sU[ig][oc] = su; sB[ig][oc] = sb;
  __syncthreads();
  if (t < 32) {
    float tu = 0.f, tb = 0.f;
#pragma unroll
    for (int i = 0; i < 8; ++i) { tu += sU[i][t]; tb += sB[i][t]; }
    if (u)  u[ob + t] = tu;
    if (bb) bb[ob + t] = tb + (bias ? bias[ob + t] : 0.f);
  }
}

// ---------------------------------------------------------------------------
// proj: bf16 MFMA GEMM on RAW x (LN folded into epilogue).
// Staging now uses dwordx4 loads: thread = (pos-quad, ch-group-of-8).
// ---------------------------------------------------------------------------
__global__ __launch_bounds__(256) void proj_mfma(
    const float* __restrict__ xq, const float* __restrict__ xk, const float* __restrict__ xv,
    const ushort_t* __restrict__ WqT, const ushort_t* __restrict__ WkT, const ushort_t* __restrict__ WvT,
    const float* __restrict__ uq, const float* __restrict__ uk, const float* __restrict__ uv,
    const float* __restrict__ bbq, const float* __restrict__ bbk, const float* __restrict__ bbv,
    ushort_t* __restrict__ Qh, ushort_t* __restrict__ Kh, ushort_t* __restrict__ Vt) {
  int blk = blockIdx.x;
  const float* x; const ushort_t* WT; const float* u; const float* bb;
  ushort_t* out; int S, ntile, vmode; float oscale;
  if (blk < 192)      { x=xq; WT=WqT; u=uq; bb=bbq; out=Qh; S=SQL; ntile=16; vmode=0; oscale=QSCALE; }
  else if (blk < 516) { blk-=192; x=xk; WT=WkT; u=uk; bb=bbk; out=Kh; S=SKL; ntile=27; vmode=0; oscale=1.f; }
  else                { blk-=516; x=xv; WT=WvT; u=uv; bb=bbv; out=Vt; S=SKL; ntile=27; vmode=1; oscale=1.f; }
  const int bn = blk / ntile;
  const int pos0 = (blk - bn * ntile) * 64;
  int valid = S - pos0; if (valid > 64) valid = 64;   // 64 or 16

  const int t = threadIdx.x;
  __shared__ ushort_t sX[64 * 128];
  __shared__ float sS1[16][64], sS2[16][64];
  __shared__ float sMu[64], sRs[64];

  {  // stage + stats: thread = (pos-quad 0..15, ch-group 0..15)
    const int posq = t & 15, chg = t >> 4;
    int lp4 = 4 * posq; if (lp4 >= valid) lp4 = valid - 4;  // clamp (dup writes benign)
    const float* xb = x + ((size_t)bn * 128 + chg * 8) * S + pos0 + lp4;
    float v[8][4];
#pragma unroll
    for (int i = 0; i < 8; ++i) {
      const float4 f = *((const float4*)(xb + (size_t)i * S));
      v[i][0] = f.x; v[i][1] = f.y; v[i][2] = f.z; v[i][3] = f.w;
    }
#pragma unroll
    for (int j = 0; j < 4; ++j) {
      float s1 = 0.f, s2 = 0.f;
#pragma unroll
      for (int i = 0; i < 8; ++i) { s1 += v[i][j]; s2 += v[i][j] * v[i][j]; }
      sS1[chg][lp4 + j] = s1; sS2[chg][lp4 + j] = s2;
    }
#pragma unroll
    for (int j = 0; j < 4; ++j) {
      const int pos = lp4 + j;
      short8 pk;
#pragma unroll
      for (int i = 0; i < 8; ++i) pk[i] = (short)f2bf(v[i][j]);
      const int phys = chg ^ (pos & 7);
      *((short8*)&sX[pos * 128 + phys * 8]) = pk;
    }
  }
  __syncthreads();
  if (t < 64) {
    float a1 = 0.f, a2 = 0.f;
#pragma unroll
    for (int g = 0; g < 16; ++g) { a1 += sS1[g][t]; a2 += sS2[g][t]; }
    const float mu = a1 * (1.f / 128.f);
    sMu[t] = mu; sRs[t] = rsqrtf(a2 * (1.f / 128.f) - mu * mu + 1e-5f);
  }
  __syncthreads();

  const int w = t >> 6, l = t & 63, lq = l & 15, quad = l >> 4;
  short8 af[2][4];
#pragma unroll
  for (int ms = 0; ms < 2; ++ms)
#pragma unroll
    for (int kk = 0; kk < 4; ++kk)
      af[ms][kk] = *((const short8*)(WT + (size_t)(w * 32 + ms * 16 + lq) * 128 + quad * 8 + kk * 32));
  f32x4 acc[4][2];
#pragma unroll
  for (int ns = 0; ns < 4; ++ns)
#pragma unroll
    for (int ms = 0; ms < 2; ++ms) acc[ns][ms] = (f32x4){0.f, 0.f, 0.f, 0.f};
#pragma unroll
  for (int ns = 0; ns < 4; ++ns) {
    short8 bf[4];
#pragma unroll
    for (int kk = 0; kk < 4; ++kk) {
      const int phys = (quad + 4 * kk) ^ (lq & 7);
      bf[kk] = *((const short8*)&sX[(ns * 16 + lq) * 128 + phys * 8]);
    }
#pragma unroll
    for (int ms = 0; ms < 2; ++ms) {
      f32x4 a = acc[ns][ms];
#pragma unroll
      for (int kk = 0; kk < 4; ++kk) a = MFMA16(af[ms][kk], bf[kk], a, 0, 0, 0);
      acc[ns][ms] = a;
    }
  }

  const int b_ = bn / NCAM, cam = bn - b_ * NCAM;
  const size_t slab = (size_t)((b_ * NHEAD + w) * NCAM + cam);
#pragma unroll
  for (int ms = 0; ms < 2; ++ms) {
    float uu[4], bv_[4];
#pragma unroll
    for (int r = 0; r < 4; ++r) {
      const int og = w * 32 + ms * 16 + quad * 4 + r;
      uu[r] = u[og]; bv_[r] = bb[og];
    }
#pragma unroll
    for (int ns = 0; ns < 4; ++ns) {
      const int p = ns * 16 + lq;
      if (p < valid) {
        const float mu = sMu[p], rs = sRs[p];
        float val[4];
#pragma unroll
        for (int r = 0; r < 4; ++r)
          val[r] = ((acc[ns][ms][r] - mu * uu[r]) * rs + bv_[r]) * oscale;
        if (vmode == 0) {
          ushort_t e0 = f2bf(val[0]), e1 = f2bf(val[1]), e2 = f2bf(val[2]), e3 = f2bf(val[3]);
          ushort_t* orow = out + (slab * S + pos0 + p) * 32 + ms * 16 + quad * 4;
          *((uint_t*)orow) = (uint_t)e0 | ((uint_t)e1 << 16);
          *((uint_t*)(orow + 2)) = (uint_t)e2 | ((uint_t)e3 << 16);
        } else {
#pragma unroll
          for (int r = 0; r < 4; ++r)
            out[(slab * 32 + ms * 16 + quad * 4 + r) * (size_t)SKL + pos0 + p] = f2bf(val[r]);
        }
      }
    }
  }
}

// ---------------------------------------------------------------------------
// MFMA flash attention, no-max softmax (exp2; scale folded into Q).
// Grid 256 blocks (bm in low 3 bits -> XCD L2 locality), 512 thr = 8 waves.
// Wave w: cam-triple (w>>2), key-quarter (w&3); processes TWO Q fragments
// (q0, q0+16) against the same K/V registers -> half the L2 requests/query.
// ---------------------------------------------------------------------------
__global__ __launch_bounds__(512, 2) void attn_mfma(
    const ushort_t* __restrict__ Qh, const ushort_t* __restrict__ Kh,
    const ushort_t* __restrict__ Vt, ushort_t* __restrict__ Ab) {
  const int t = threadIdx.x;
  const int w = t >> 6, l = t & 63;
  const int lq = l & 15, quad = l >> 4;
  const int bm = blockIdx.x & 7;
  const int q0 = (blockIdx.x >> 3) * 32;
  const int camg = w >> 2, kq = w & 3;
  const int kstart = kq * 448;
  const int nfull = (kq == 3) ? 5 : 7;

  __shared__ ushort_t sP[8][2][16][72];
  __shared__ float sO[8][2][16][36];
  __shared__ float sL[8][2][16];

  f32x4 oA0 = {0.f,0.f,0.f,0.f}, oA1 = {0.f,0.f,0.f,0.f};
  f32x4 oB0 = {0.f,0.f,0.f,0.f}, oB1 = {0.f,0.f,0.f,0.f};
  float lA = 0.f, lB = 0.f;

  for (int nc = 0; nc < 3; ++nc) {
    const int n = camg * 3 + nc;
    const ushort_t* Kb = Kh + (size_t)(bm * NCAM + n) * SKL * 32;
    const ushort_t* Vb = Vt + (size_t)(bm * NCAM + n) * 32 * SKL;
    const ushort_t* Qbase = Qh + ((size_t)(bm * NCAM + n) * SQL + q0) * 32;
    const short8 qfA = *((const short8*)(Qbase + (size_t)lq * 32 + quad * 8));
    const short8 qfB = *((const short8*)(Qbase + (size_t)(16 + lq) * 32 + quad * 8));

    for (int kt = 0; kt < nfull; ++kt) {
      const int kb = kstart + kt * 64;
      short8 kf[4];
#pragma unroll
      for (int st = 0; st < 4; ++st)
        kf[st] = *((const short8*)(Kb + (size_t)(kb + st * 16 + lq) * 32 + quad * 8));
      const short8 v00 = *((const short8*)(Vb + (size_t)lq * SKL + kb + quad * 8));
      const short8 v01 = *((const short8*)(Vb + (size_t)lq * SKL + kb + 32 + quad * 8));
      const short8 v10 = *((const short8*)(Vb + (size_t)(16 + lq) * SKL + kb + quad * 8));
      const short8 v11 = *((const short8*)(Vb + (size_t)(16 + lq) * SKL + kb + 32 + quad * 8));

      f32x4 sA[4], sB[4];
#pragma unroll
      for (int st = 0; st < 4; ++st) {
        f32x4 z = {0.f, 0.f, 0.f, 0.f};
        sA[st] = MFMA16(kf[st], qfA, z, 0, 0, 0);
        sB[st] = MFMA16(kf[st], qfB, z, 0, 0, 0);
      }
      float lsA = 0.f, lsB = 0.f;
#pragma unroll
      for (int st = 0; st < 4; ++st) {
        const float a0 = __builtin_amdgcn_exp2f(sA[st][0]);
        const float a1 = __builtin_amdgcn_exp2f(sA[st][1]);
        const float a2 = __builtin_amdgcn_exp2f(sA[st][2]);
        const float a3 = __builtin_amdgcn_exp2f(sA[st][3]);
        const float b0 = __builtin_amdgcn_exp2f(sB[st][0]);
        const float b1 = __builtin_amdgcn_exp2f(sB[st][1]);
        const float b2 = __builtin_amdgcn_exp2f(sB[st][2]);
        const float b3 = __builtin_amdgcn_exp2f(sB[st][3]);
        lsA += (a0 + a1) + (a2 + a3);
        lsB += (b0 + b1) + (b2 + b3);
        const uint_t pa0 = __builtin_amdgcn_perm(__builtin_bit_cast(uint_t, a1), __builtin_bit_cast(uint_t, a0), 0x07060302u);
        const uint_t pa1 = __builtin_amdgcn_perm(__builtin_bit_cast(uint_t, a3), __builtin_bit_cast(uint_t, a2), 0x07060302u);
        const uint_t pb0 = __builtin_amdgcn_perm(__builtin_bit_cast(uint_t, b1), __builtin_bit_cast(uint_t, b0), 0x07060302u);
        const uint_t pb1 = __builtin_amdgcn_perm(__builtin_bit_cast(uint_t, b3), __builtin_bit_cast(uint_t, b2), 0x07060302u);
        *((uint2*)&sP[w][0][lq][st * 16 + quad * 4]) = make_uint2(pa0, pa1);
        *((uint2*)&sP[w][1][lq][st * 16 + quad * 4]) = make_uint2(pb0, pb1);
      }
      const short8 pfA0 = *((const short8*)&sP[w][0][lq][quad * 8]);
      const short8 pfA1 = *((const short8*)&sP[w][0][lq][32 + quad * 8]);
      const short8 pfB0 = *((const short8*)&sP[w][1][lq][quad * 8]);
      const short8 pfB1 = *((const short8*)&sP[w][1][lq][32 + quad * 8]);
      oA0 = MFMA16(v00, pfA0, oA0, 0, 0, 0);
      oA1 = MFMA16(v10, pfA0, oA1, 0, 0, 0);
      oB0 = MFMA16(v00, pfB0, oB0, 0, 0, 0);
      oB1 = MFMA16(v10, pfB0, oB1, 0, 0, 0);
      oA0 = MFMA16(v01, pfA1, oA0, 0, 0, 0);
      oA1 = MFMA16(v11, pfA1, oA1, 0, 0, 0);
      oB0 = MFMA16(v01, pfB1, oB0, 0, 0, 0);
      oB1 = MFMA16(v11, pfB1, oB1, 0, 0, 0);
      lsA += __shfl_xor(lsA, 16, 64);
      lsA += __shfl_xor(lsA, 32, 64);
      lsB += __shfl_xor(lsB, 16, 64);
      lsB += __shfl_xor(lsB, 32, 64);
      lA += lsA; lB += lsB;
    }

    if (kq == 3) {  // 16-key tail (keys 1664..1679)
      const int kb = kstart + 320;
      const short8 kf = *((const short8*)(Kb + (size_t)(kb + lq) * 32 + quad * 8));
      const short8 v00 = *((const short8*)(Vb + (size_t)lq * SKL + kb + quad * 8));
      const short8 v10 = *((const short8*)(Vb + (size_t)(16 + lq) * SKL + kb + quad * 8));
      f32x4 z = {0.f, 0.f, 0.f, 0.f};
      const f32x4 s0A = MFMA16(kf, qfA, z, 0, 0, 0);
      const f32x4 s0B = MFMA16(kf, qfB, z, 0, 0, 0);
      const float a0 = __builtin_amdgcn_exp2f(s0A[0]);
      const float a1 = __builtin_amdgcn_exp2f(s0A[1]);
      const float a2 = __builtin_amdgcn_exp2f(s0A[2]);
      const float a3 = __builtin_amdgcn_exp2f(s0A[3]);
      const float b0 = __builtin_amdgcn_exp2f(s0B[0]);
      const float b1 = __builtin_amdgcn_exp2f(s0B[1]);
      const float b2 = __builtin_amdgcn_exp2f(s0B[2]);
      const float b3 = __builtin_amdgcn_exp2f(s0B[3]);
      float lsA = (a0 + a1) + (a2 + a3);
      float lsB = (b0 + b1) + (b2 + b3);
      const uint_t pa0 = __builtin_amdgcn_perm(__builtin_bit_cast(uint_t, a1), __builtin_bit_cast(uint_t, a0), 0x07060302u);
      const uint_t pa1 = __builtin_amdgcn_perm(__builtin_bit_cast(uint_t, a3), __builtin_bit_cast(uint_t, a2), 0x07060302u);
      const uint_t pb0 = __builtin_amdgcn_perm(__builtin_bit_cast(uint_t, b1), __builtin_bit_cast(uint_t, b0), 0x07060302u);
      const uint_t pb1 = __builtin_amdgcn_perm(__builtin_bit_cast(uint_t, b3), __builtin_bit_cast(uint_t, b2), 0x07060302u);
      *((uint2*)&sP[w][0][lq][quad * 4]) = make_uint2(pa0, pa1);
      *((uint2*)&sP[w][0][lq][16 + quad * 4]) = make_uint2(0u, 0u);
      *((uint2*)&sP[w][1][lq][quad * 4]) = make_uint2(pb0, pb1);
      *((uint2*)&sP[w][1][lq][16 + quad * 4]) = make_uint2(0u, 0u);
      const short8 pfA0 = *((const short8*)&sP[w][0][lq][quad * 8]);
      const short8 pfB0 = *((const short8*)&sP[w][1][lq][quad * 8]);
      oA0 = MFMA16(v00, pfA0, oA0, 0, 0, 0);
      oA1 = MFMA16(v10, pfA0, oA1, 0, 0, 0);
      oB0 = MFMA16(v00, pfB0, oB0, 0, 0, 0);
      oB1 = MFMA16(v10, pfB0, oB1, 0, 0, 0);
      lsA += __shfl_xor(lsA, 16, 64);
      lsA += __shfl_xor(lsA, 32, 64);
      lsB += __shfl_xor(lsB, 16, 64);
      lsB += __shfl_xor(lsB, 32, 64);
      lA += lsA; lB += lsB;
    }
  }

  // combine 8 key-partitions per fragment (pure sums — no max tracking)
  *((f32x4*)&sO[w][0][lq][quad * 4]) = oA0;
  *((f32x4*)&sO[w][0][lq][16 + quad * 4]) = oA1;
  *((f32x4*)&sO[w][1][lq][quad * 4]) = oB0;
  *((f32x4*)&sO[w][1][lq][16 + quad * 4]) = oB1;
  if (l < 16) { sL[w][0][l] = lA; sL[w][1][l] = lB; }
  __syncthreads();
  if (w < 2) {
    const int frag = w;
    float lf = 0.f;
    f32x4 a0 = {0.f, 0.f, 0.f, 0.f}, a1 = {0.f, 0.f, 0.f, 0.f};
#pragma unroll
    for (int ww = 0; ww < 8; ++ww) {
      lf += sL[ww][frag][lq];
      a0 += *((const f32x4*)&sO[ww][frag][lq][quad * 4]);
      a1 += *((const f32x4*)&sO[ww][frag][lq][16 + quad * 4]);
    }
    const float inv = 1.f / lf;
    const int b = bm >> 2, hm = bm & 3;
    ushort_t* op = Ab + ((size_t)b * SQL + q0 + frag * 16 + lq) * 128 + hm * 32 + quad * 4;
    ushort4 w0 = make_ushort4(f2bf(a0[0] * inv), f2bf(a0[1] * inv), f2bf(a0[2] * inv), f2bf(a0[3] * inv));
    ushort4 w1 = make_ushort4(f2bf(a1[0] * inv), f2bf(a1[1] * inv), f2bf(a1[2] * inv), f2bf(a1[3] * inv));
    *((ushort4*)op) = w0;
    *((ushort4*)(op + 16)) = w1;
  }
}

// ---------------------------------------------------------------------------
// post: a@Wp + skip -> preLN -> gelu(n@W1''+b1'')@W2 + res -> postLN -> out.
// ---------------------------------------------------------------------------
__global__ __launch_bounds__(256) void post_mfma(
    const ushort_t* __restrict__ Ab, const float* __restrict__ skip,
    const ushort_t* __restrict__ WpT, const float* __restrict__ bp,
    const float* __restrict__ pre_g, const float* __restrict__ pre_b,
    const ushort_t* __restrict__ W1T, const float* __restrict__ b1p,
    const ushort_t* __restrict__ W2T, const float* __restrict__ b2,
    const float* __restrict__ post_g, const float* __restrict__ post_b,
    float* __restrict__ out) {
  const int t = threadIdx.x;
  const int w = t >> 6, l = t & 63, lq = l & 15, quad = l >> 4;
  const int b = blockIdx.x >> 6;
  const int p0 = (blockIdx.x & 63) * 16;

  __shared__ float zf[16 * 132];
  __shared__ float sRes[16 * 132];
  __shared__ ushort_t sZb[16 * 128];
  __shared__ ushort_t sH[16 * 256];
  __shared__ float sMu[16], sRs[16];

  // ---- GEMM1: z = a@Wp ----
  f32x4 z[2] = {{0.f,0.f,0.f,0.f},{0.f,0.f,0.f,0.f}};
#pragma unroll
  for (int kk = 0; kk < 4; ++kk) {
    const short8 bfr = *((const short8*)(Ab + ((size_t)b * SQL + p0 + lq) * 128 + quad * 8 + kk * 32));
#pragma unroll
    for (int ms = 0; ms < 2; ++ms) {
      const short8 afr = *((const short8*)(WpT + (size_t)(w * 32 + ms * 16 + lq) * 128 + quad * 8 + kk * 32));
      z[ms] = MFMA16(afr, bfr, z[ms], 0, 0, 0);
    }
  }
#pragma unroll
  for (int ms = 0; ms < 2; ++ms)
#pragma unroll
    for (int r = 0; r < 4; ++r) {
      const int o = w * 32 + ms * 16 + quad * 4 + r;
      zf[lq * 132 + o] = z[ms][r] + bp[o] + skip[(size_t)b * 131072 + (size_t)o * 1024 + p0 + lq];
    }
  __syncthreads();
  if (w == 0) {
    const int pos = l & 15, qr = l >> 4;
    float s1 = 0.f, s2 = 0.f;
#pragma unroll
    for (int j = 0; j < 32; ++j) { const float vv = zf[pos * 132 + qr * 32 + j]; s1 += vv; s2 += vv * vv; }
    s1 += __shfl_xor(s1, 16, 64); s1 += __shfl_xor(s1, 32, 64);
    s2 += __shfl_xor(s2, 16, 64); s2 += __shfl_xor(s2, 32, 64);
    const float mu = s1 * (1.f / 128.f);
    if (qr == 0) { sMu[pos] = mu; sRs[pos] = rsqrtf(s2 * (1.f / 128.f) - mu * mu + 1e-5f); }
  }
  __syncthreads();
  {
    const int pos = t & 15, grp = t >> 4;
    const float mu = sMu[pos], rs = sRs[pos];
    short8 pk;
#pragma unroll
    for (int i = 0; i < 8; ++i) {
      const int ch = grp * 8 + i;
      const float nv = (zf[pos * 132 + ch] - mu) * rs;
      pk[i] = (short)f2bf(nv);
      sRes[pos * 132 + ch] = nv * pre_g[ch] + pre_b[ch];
    }
    *((short8*)&sZb[pos * 128 + (grp ^ (pos & 7)) * 8]) = pk;
  }
  __syncthreads();
  // ---- GEMM2 + gelu ----
  f32x4 h[4];
#pragma unroll
  for (int ms = 0; ms < 4; ++ms) h[ms] = (f32x4){0.f, 0.f, 0.f, 0.f};
  short8 bz[4];
#pragma unroll
  for (int kk = 0; kk < 4; ++kk)
    bz[kk] = *((const short8*)&sZb[lq * 128 + ((quad + 4 * kk) ^ (lq & 7)) * 8]);
#pragma unroll
  for (int ms = 0; ms < 4; ++ms)
#pragma unroll
    for (int kk = 0; kk < 4; ++kk) {
      const short8 afr = *((const short8*)(W1T + (size_t)(w * 64 + ms * 16 + lq) * 128 + quad * 8 + kk * 32));
      h[ms] = MFMA16(afr, bz[kk], h[ms], 0, 0, 0);
    }
#pragma unroll
  for (int ms = 0; ms < 4; ++ms)
#pragma unroll
    for (int r = 0; r < 4; ++r) {
      const int o = w * 64 + ms * 16 + quad * 4 + r;
      const float hv = fast_gelu(h[ms][r] + b1p[o]);
      const int phys = (o >> 3) ^ (lq & 7);
      sH[lq * 256 + phys * 8 + (o & 7)] = f2bf(hv);
    }
  __syncthreads();
  // ---- GEMM3 + residual ----
  f32x4 z2[2] = {{0.f,0.f,0.f,0.f},{0.f,0.f,0.f,0.f}};
#pragma unroll
  for (int kk = 0; kk < 8; ++kk) {
    const short8 bh = *((const short8*)&sH[lq * 256 + ((quad + 4 * kk) ^ (lq & 7)) * 8]);
#pragma unroll
    for (int ms = 0; ms < 2; ++ms) {
      const short8 afr = *((const short8*)(W2T + (size_t)(w * 32 + ms * 16 + lq) * 256 + quad * 8 + kk * 32));
      z2[ms] = MFMA16(afr, bh, z2[ms], 0, 0, 0);
    }
  }
  __syncthreads();
#pragma unroll
  for (int ms = 0; ms < 2; ++ms)
#pragma unroll
    for (int r = 0; r < 4; ++r) {
      const int o = w * 32 + ms * 16 + quad * 4 + r;
      zf[lq * 132 + o] = z2[ms][r] + b2[o] + sRes[lq * 132 + o];
    }
  __syncthreads();
  if (w == 0) {
    const int pos = l & 15, qr = l >> 4;
    float s1 = 0.f, s2 = 0.f;
#pragma unroll
    for (int j = 0; j < 32; ++j) { const float vv = zf[pos * 132 + qr * 32 + j]; s1 += vv; s2 += vv * vv; }
    s1 += __shfl_xor(s1, 16, 64); s1 += __shfl_xor(s1, 32, 64);
    s2 += __shfl_xor(s2, 16, 64); s2 += __shfl_xor(s2, 32, 64);
    const float mu = s1 * (1.f / 128.f);
    if (qr == 0) { sMu[pos] = mu; sRs[pos] = rsqrtf(s2 * (1.f / 128.f) + 1e-5f - mu * mu + mu * mu - mu * mu); }
  }
  __syncthreads();
  {
    const int pos = t & 15, grp = t >> 4;
    const float mu = sMu[pos], rs = sRs[pos];
#pragma unroll
    for (int i = 0; i < 8; ++i) {
      const int ch = grp * 8 + i;
      out[(size_t)b * 131072 + (size_t)ch * 1024 + p0 + pos] =
          (zf[pos * 132 + ch] - mu) * rs * post_g[ch] + post_b[ch];
    }
  }
}

// ---------------------------------------------------------------------------
extern "C" void kernel_launch(void* const* d_in, const int* in_sizes, int n_in,
                              void* d_out, int out_size, void* d_ws, size_t ws_size,
                              hipStream_t stream) {
  const float* q_in   = (const float*)d_in[0];
  const float* k_in   = (const float*)d_in[1];
  const float* v_in   = (const float*)d_in[2];
  const float* skip   = (const float*)d_in[3];
  const float* q_ln_g = (const float*)d_in[4];
  const float* q_ln_b = (const float*)d_in[5];
  const float* Wq     = (const float*)d_in[6];
  const float* bq     = (const float*)d_in[7];
  const float* k_ln_g = (const float*)d_in[8];
  const float* k_ln_b = (const float*)d_in[9];
  const float* Wk     = (const float*)d_in[10];
  const float* bk     = (const float*)d_in[11];
  const float* v_ln_g = (const float*)d_in[12];
  const float* v_ln_b = (const float*)d_in[13];
  const float* Wv     = (const float*)d_in[14];
  const float* bv     = (const float*)d_in[15];
  const float* Wp     = (const float*)d_in[16];
  const float* bp     = (const float*)d_in[17];
  const float* pre_g  = (const float*)d_in[18];
  const float* pre_b  = (const float*)d_in[19];
  const float* W1     = (const float*)d_in[20];
  const float* b1     = (const float*)d_in[21];
  const float* W2     = (const float*)d_in[22];
  const float* b2     = (const float*)d_in[23];
  const float* post_g = (const float*)d_in[24];
  const float* post_b = (const float*)d_in[25];

  char* base = (char*)d_ws;
  ushort_t* WqT = (ushort_t*)base; base += 16384 * 2;
  ushort_t* WkT = (ushort_t*)base; base += 16384 * 2;
  ushort_t* WvT = (ushort_t*)base; base += 16384 * 2;
  ushort_t* WpT = (ushort_t*)base; base += 16384 * 2;
  ushort_t* W1T = (ushort_t*)base; base += 32768 * 2;
  ushort_t* W2T = (ushort_t*)base; base += 32768 * 2;
  float* uq  = (float*)base; base += 128 * 4;
  float* bbq = (float*)base; base += 128 * 4;
  float* uk  = (float*)base; base += 128 * 4;
  float* bbk = (float*)base; base += 128 * 4;
  float* uv  = (float*)base; base += 128 * 4;
  float* bbv = (float*)base; base += 128 * 4;
  float* b1p = (float*)base; base += 256 * 4;
  base = (char*)(((size_t)base + 255) & ~(size_t)255);
  ushort_t* Qh = (ushort_t*)base; base += (size_t)1572864 * 2;
  ushort_t* Kh = (ushort_t*)base; base += (size_t)(2580480 + 4096) * 2;
  ushort_t* Vt = (ushort_t*)base; base += (size_t)(2580480 + 4096) * 2;
  ushort_t* Ab = (ushort_t*)base; base += (size_t)262144 * 2;
  float* out = (float*)d_out;

  prep_kernel<<<28, 256, 0, stream>>>(
      Wq, q_ln_g, q_ln_b, bq, Wk, k_ln_g, k_ln_b, bk, Wv, v_ln_g, v_ln_b, bv,
      Wp, W1, pre_g, pre_b, b1, W2,
      WqT, WkT, WvT, WpT, W1T, W2T, uq, bbq, uk, bbk, uv, bbv, b1p);
  proj_mfma<<<840, 256, 0, stream>>>(
      q_in, k_in, v_in, WqT, WkT, WvT, uq, uk, uv, bbq, bbk, bbv, Qh, Kh, Vt);
  attn_mfma<<<256, 512, 0, stream>>>(Qh, Kh, Vt, Ab);
  post_mfma<<<128, 256, 0, stream>>>(
      Ab, skip, WpT, bp, pre_g, pre_b, W1T, b1p, W2T, b2, post_g, post_b, out);
}